// Round 10
// baseline (503.693 us; speedup 1.0000x reference)
//
#include <hip/hip_runtime.h>
#include <cmath>

#define NPTS 10000
#define NBATCH 8
#define NFEAT 16
#define DDIM 128
#define NBINS 20
#define BINSZ 500
#define KSEL 5
#define EDGES_PER_BATCH (NPTS*KSEL)        // 50000
#define EDGE_TOT (NBATCH*EDGES_PER_BATCH)  // 400000
#define TOTPTS (NBATCH*NPTS)               // 80000
#define NGRP (NBATCH*NBINS)                // 160
#define PROWS 512                          // padded rows per (grp,ch) partial slab

typedef _Float16 f16x8 __attribute__((ext_vector_type(8)));
typedef float f32x4 __attribute__((ext_vector_type(4)));
typedef unsigned short u16;
typedef unsigned int u32;

// fp32 -> (Hs, D): Hs = 64*fp16(x), D = fp16((x - fp16(x)) * 64).
// Products then need no runtime scaling:
//   Hs*D = h*l, D*Hs = l*h, Hs*Hs = 4096*h*h ;  S = acc * 2^-12.
static __device__ __forceinline__ void split_f16(float v, u16& hu, u16& du) {
    _Float16 h = (_Float16)v;
    float hf = (float)h;
    if (fabsf(v) < 6.103515625e-05f) { h = (_Float16)0.0f; hf = 0.0f; }
    _Float16 Hs = h * (_Float16)64.0f;              // exact (exponent shift)
    _Float16 D  = (_Float16)((v - hf) * 64.0f);
    hu = __builtin_bit_cast(u16, Hs);
    du = __builtin_bit_cast(u16, D);
}

// enc = ELU(X@W1+b1)@W2+b2, stored as P[row][256] = [Hs(128) | D(128)] f16.
// v10 = v9 (fused bins) with the INS_TIE transcription bug fixed (PP[3]=PP[2]
// line had degenerated to PP[2]=PP[2] in r9 — corrupted every tie-merge).
// Fused bins: mul = enc @ R[:,:10] from the fp32 acc registers (no 41 MB
// enc re-read, one fewer kernel): per-thread 4x4 partial vs an R-transpose
// LDS tile, 5-step shfl_xor tree over the 32 dim-threads per point-group,
// lane jt==0 does argmax (identical first-max-wins code as the old k_bins)
// + hist atomic. hist pre-zeroed via hipMemsetAsync.
__global__ __launch_bounds__(256) void k_enc(const float* __restrict__ X,
        const float* __restrict__ W1, const float* __restrict__ b1,
        const float* __restrict__ W2, const float* __restrict__ b2,
        const float* __restrict__ R,
        u16* __restrict__ P, int* __restrict__ binIdx, int* __restrict__ hist) {
    __shared__ float hT[128*36];
    __shared__ float Rt[10*128];            // Rt[i][d] = R[d*100+i]
    const int tid = threadIdx.x;
    const int P0 = blockIdx.x * 32;
    for (int idx = tid; idx < 1280; idx += 256) {
        int i = idx >> 7, d = idx & 127;
        Rt[idx] = R[d*100 + i];
    }
    #pragma unroll
    for (int i = 0; i < 16; ++i) {
        int idx = i*256 + tid;
        int p = idx >> 7;
        int j = idx & 127;
        const float* xr = X + (size_t)(P0 + p)*NFEAT;
        float h = b1[j];
        #pragma unroll
        for (int f = 0; f < 16; ++f) h += xr[f] * W1[f*128 + j];
        h = (h > 0.f) ? h : expm1f(h);
        hT[j*36 + p] = h;
    }
    __syncthreads();
    const int jt = tid & 31, pt = tid >> 5;
    const int j0 = jt*4, p0 = pt*4;
    float acc[4][4];
    #pragma unroll
    for (int ep = 0; ep < 4; ++ep)
        #pragma unroll
        for (int ej = 0; ej < 4; ++ej) acc[ep][ej] = b2[j0+ej];
    for (int k = 0; k < 128; ++k) {
        float4 hv = *(const float4*)&hT[k*36 + p0];
        float4 wv = *(const float4*)&W2[k*128 + j0];
        float hvv[4] = {hv.x,hv.y,hv.z,hv.w};
        float wvv[4] = {wv.x,wv.y,wv.z,wv.w};
        #pragma unroll
        for (int ep = 0; ep < 4; ++ep)
            #pragma unroll
            for (int ej = 0; ej < 4; ++ej) acc[ep][ej] += hvv[ep]*wvv[ej];
    }
    // ---- bins partials (from fp32 acc — matches reference precision) ----
    float mul[4][10];
    #pragma unroll
    for (int i = 0; i < 10; ++i) {
        float4 rv = *(const float4*)&Rt[i*128 + j0];
        #pragma unroll
        for (int ep = 0; ep < 4; ++ep)
            mul[ep][i] = acc[ep][0]*rv.x + acc[ep][1]*rv.y
                       + acc[ep][2]*rv.z + acc[ep][3]*rv.w;
    }
    // ---- store P (frees acc before the shfl tree) ----
    #pragma unroll
    for (int ep = 0; ep < 4; ++ep) {
        u16 hs[4], ds[4];
        #pragma unroll
        for (int ej = 0; ej < 4; ++ej) split_f16(acc[ep][ej], hs[ej], ds[ej]);
        size_t ro = (size_t)(P0+p0+ep)*256 + j0;
        uint2 hv2, dv2;
        hv2.x = (u32)hs[0] | ((u32)hs[1]<<16); hv2.y = (u32)hs[2] | ((u32)hs[3]<<16);
        dv2.x = (u32)ds[0] | ((u32)ds[1]<<16); dv2.y = (u32)ds[2] | ((u32)ds[3]<<16);
        *(uint2*)&P[ro]       = hv2;
        *(uint2*)&P[ro + 128] = dv2;
    }
    // ---- reduce mul over the 32 jt-lanes (masks 1..16 stay in-half) ----
    #pragma unroll
    for (int m = 1; m <= 16; m <<= 1)
        #pragma unroll
        for (int ep = 0; ep < 4; ++ep)
            #pragma unroll
            for (int i = 0; i < 10; ++i)
                mul[ep][i] += __shfl_xor(mul[ep][i], m, 64);
    if (jt == 0) {
        #pragma unroll
        for (int ep = 0; ep < 4; ++ep) {
            float best = mul[ep][0]; int bi = 0;
            #pragma unroll
            for (int i = 1; i < 10; ++i) if (mul[ep][i] > best) { best = mul[ep][i]; bi = i; }
            #pragma unroll
            for (int i = 0; i < 10; ++i) { float v = -mul[ep][i]; if (v > best) { best = v; bi = 10+i; } }
            int gp = P0 + p0 + ep;
            binIdx[gp] = bi;
            atomicAdd(&hist[(gp/NPTS)*NBINS + bi], 1);
        }
    }
}

// stable counting-sort scatter: one block per (batch,bin)
__global__ __launch_bounds__(256) void k_sort(const int* __restrict__ binIdx,
        const int* __restrict__ hist, int* __restrict__ sortedIdx) {
    const int b = blockIdx.x / NBINS;
    const int bin = blockIdx.x % NBINS;
    const int tid = threadIdx.x;
    __shared__ int wtot[4];
    int off = 0;
    for (int k = 0; k < bin; ++k) off += hist[b*NBINS + k];
    const int* bptr = binIdx + b*NPTS;
    int* sptr = sortedIdx + b*NPTS;
    const int lane = tid & 63, wid = tid >> 6;
    for (int c = 0; c < 40; ++c) {
        int i = c*256 + tid;
        bool pred = (i < NPTS) && (bptr[i] == bin);
        unsigned long long mask = __ballot(pred);
        int rank = __popcll(mask & ((1ULL << lane) - 1ULL));
        if (lane == 0) wtot[wid] = __popcll(mask);
        __syncthreads();
        int prefix = 0;
        #pragma unroll
        for (int w = 0; w < 4; ++w) prefix += (w < wid) ? wtot[w] : 0;
        int total = wtot[0]+wtot[1]+wtot[2]+wtot[3];
        if (pred) sptr[off + prefix + rank] = i;
        off += total;
        __syncthreads();
    }
}

// insert (v,p) into sorted-desc 5-list, strict > (candidates arrive ascending p)
#define INS_STRICT(VV,PP,v,p) do { \
  if ((v) > VV[4]) { \
    if ((v) > VV[3]) { VV[4]=VV[3]; PP[4]=PP[3]; \
      if ((v) > VV[2]) { VV[3]=VV[2]; PP[3]=PP[2]; \
        if ((v) > VV[1]) { VV[2]=VV[1]; PP[2]=PP[1]; \
          if ((v) > VV[0]) { VV[1]=VV[0]; PP[1]=PP[0]; VV[0]=(v); PP[0]=(p); } \
          else { VV[1]=(v); PP[1]=(p); } } \
        else { VV[2]=(v); PP[2]=(p); } } \
      else { VV[3]=(v); PP[3]=(p); } } \
    else { VV[4]=(v); PP[4]=(p); } } } while(0)

// tie-aware better-than: (v desc, p asc) — exact lax.top_k semantics
#define BT(va,pa,vb,pb) (((va) > (vb)) || (((va) == (vb)) && ((pa) < (pb))))
#define INS_TIE(VV,PP,v,p) do { \
  if (BT(v,p,VV[4],PP[4])) { \
    if (BT(v,p,VV[3],PP[3])) { VV[4]=VV[3]; PP[4]=PP[3]; \
      if (BT(v,p,VV[2],PP[2])) { VV[3]=VV[2]; PP[3]=PP[2]; \
        if (BT(v,p,VV[1],PP[1])) { VV[2]=VV[1]; PP[2]=PP[1]; \
          if (BT(v,p,VV[0],PP[0])) { VV[1]=VV[0]; PP[1]=PP[0]; VV[0]=(v); PP[0]=(p); } \
          else { VV[1]=(v); PP[1]=(p); } } \
        else { VV[2]=(v); PP[2]=(p); } } \
      else { VV[3]=(v); PP[3]=(p); } } \
    else { VV[4]=(v); PP[4]=(p); } } } while(0)

// Gram via f16 MFMA with pre-scaled split operands (zero runtime scaling):
//   acc = Hs_a·D_b + D_a·Hs_b + Hs_a·Hs_b ;  S = acc·2^-12
// r5-verified structure (94 µs): T[64][132] 2-pass epilogue, LDS 35840,
// launch_bounds(256,4). r6: (256,6) spills acc (750MB scratch). r7: 32-row
// 4-pass epilogue serializes (157µs). r8: A-prefetch neutral — kept.
__global__ __launch_bounds__(256, 4) void k_gram(const u16* __restrict__ P,
        const int* __restrict__ sortedIdx, float* __restrict__ pV, int* __restrict__ pP) {
    __shared__ int gIdx[512];
    __shared__ __align__(16) union ShU {
        struct { u16 H[128][40]; u16 L[128][40]; } bs;   // 20480 B
        float T[64][132];                                // 33792 B
    } sh;
    const int tid = threadIdx.x;
    const int unit = blockIdx.x / 160;      // rowTile*4 + ch
    const int grp  = blockIdx.x - unit*160;
    const int rowTile = unit >> 2, ch = unit & 3;
    const int b = grp / NBINS, g = grp - b*NBINS;
    for (int i = tid; i < 512; i += 256) gIdx[i] = sortedIdx[b*NPTS + g*500 + min(i, 499)];
    __syncthreads();

    const int w    = tid >> 6;              // wave 0..3: rows w*32..w*32+31
    const int lane = tid & 63;
    const int l15  = lane & 15, l4 = lane >> 4;
    const int rowBase = rowTile * 128;

    const size_t ebase = (size_t)b * NPTS * 256;   // halfwords
    const u16* PB = P + ebase;
    const u16* pA0 = PB + (size_t)gIdx[rowBase + w*32 +      l15]*256 + l4*8;
    const u16* pA1 = PB + (size_t)gIdx[rowBase + w*32 + 16 + l15]*256 + l4*8;

    // stager role: thread t copies the 64B ks-chunk of col (t>>1), part (t&1)
    const int scol = tid >> 1, spart = tid & 1;
    const u16* pS = PB + (size_t)gIdx[ch*128 + scol]*256 + spart*128;
    u16* dS = spart ? &sh.bs.L[scol][0] : &sh.bs.H[scol][0];

    f32x4 acc[2][8];
    const f32x4 z4 = {0.f, 0.f, 0.f, 0.f};
    #pragma unroll
    for (int rf = 0; rf < 2; ++rf)
        #pragma unroll
        for (int cf = 0; cf < 8; ++cf) acc[rf][cf] = z4;

    // prologue: stage B regs for ks=0 and A fragments for ks=0
    uint4 s0, s1, s2, s3;
    { const uint4* s = (const uint4*)pS; s0 = s[0]; s1 = s[1]; s2 = s[2]; s3 = s[3]; }
    f16x8 aH0 = *(const f16x8*)(pA0 + 0);
    f16x8 aD0 = *(const f16x8*)(pA0 + 128);
    f16x8 aH1 = *(const f16x8*)(pA1 + 0);
    f16x8 aD1 = *(const f16x8*)(pA1 + 128);

    #pragma unroll
    for (int ks = 0; ks < 4; ++ks) {
        __syncthreads();                    // prior k-step's LDS reads done
        {   // write staged B regs (data already in flight / in regs)
            uint4* d = (uint4*)dS;
            d[0] = s0; d[1] = s1; d[2] = s2; d[3] = s3;
        }
        if (ks < 3) {                       // prefetch next B chunk under MFMA
            const uint4* s = (const uint4*)(pS + (ks+1)*32);
            s0 = s[0]; s1 = s[1]; s2 = s[2]; s3 = s[3];
        }
        __syncthreads();                    // staged data visible
        #pragma unroll
        for (int cf = 0; cf < 8; ++cf) {
            const int col = cf*16 + l15;
            const f16x8 bH = *(const f16x8*)&sh.bs.H[col][l4*8];
            const f16x8 bD = *(const f16x8*)&sh.bs.L[col][l4*8];
            acc[0][cf] = __builtin_amdgcn_mfma_f32_16x16x32_f16(aH0, bD, acc[0][cf], 0, 0, 0);
            acc[1][cf] = __builtin_amdgcn_mfma_f32_16x16x32_f16(aH1, bD, acc[1][cf], 0, 0, 0);
            acc[0][cf] = __builtin_amdgcn_mfma_f32_16x16x32_f16(aD0, bH, acc[0][cf], 0, 0, 0);
            acc[1][cf] = __builtin_amdgcn_mfma_f32_16x16x32_f16(aD1, bH, acc[1][cf], 0, 0, 0);
            acc[0][cf] = __builtin_amdgcn_mfma_f32_16x16x32_f16(aH0, bH, acc[0][cf], 0, 0, 0);
            acc[1][cf] = __builtin_amdgcn_mfma_f32_16x16x32_f16(aH1, bH, acc[1][cf], 0, 0, 0);
        }
        if (ks < 3) {                       // prefetch A for ks+1
            const int oH = (ks+1)*32;
            const int oD = 128 + (ks+1)*32;
            aH0 = *(const f16x8*)(pA0 + oH);
            aD0 = *(const f16x8*)(pA0 + oD);
            aH1 = *(const f16x8*)(pA1 + oH);
            aD1 = *(const f16x8*)(pA1 + oD);
        }
    }
    __syncthreads();                        // k-loop LDS reads done; reuse as T

    // ---- epilogue: per rf-half, LDS transpose then 4-thread/row top-5 ----
    const float sc = 2.44140625e-4f;        // 2^-12, applied to survivors only
    const int rT = tid >> 2;                // 0..63: T-row this thread reduces
    const int q  = tid & 3;                 // chunk interleave c4 = 4t+q
    const bool chk = (ch == 3);             // chunks >= 29 invalid when ch==3
    #pragma unroll
    for (int rf = 0; rf < 2; ++rf) {
        #pragma unroll
        for (int cf = 0; cf < 8; ++cf) {
            const int col = cf*16 + l15;
            const int r0  = w*16 + l4*4;
            #pragma unroll
            for (int j = 0; j < 4; ++j) sh.T[r0+j][col] = acc[rf][cf][j];
        }
        __syncthreads();
        float lv[5]; int lp[5];
        #pragma unroll
        for (int p5 = 0; p5 < 5; ++p5) { lv[p5] = -3.4e38f; lp[p5] = 0x7fffffff; }
        const float* Tr = &sh.T[rT][0];
        #pragma unroll
        for (int t = 0; t < 8; ++t) {
            const int c4 = t*4 + q;         // ascending cpos per thread
            if (!chk || c4 < 29) {          // 116 valid cols = chunks 0..28
                float4 v4 = *(const float4*)&Tr[c4*4];
                float vv4[4] = {v4.x, v4.y, v4.z, v4.w};
                #pragma unroll
                for (int e = 0; e < 4; ++e)
                    INS_STRICT(lv, lp, vv4[e], ch*128 + c4*4 + e);
            }
        }
        #pragma unroll
        for (int m = 1; m < 4; m <<= 1) {
            float qv[5]; int qp[5];
            #pragma unroll
            for (int p5 = 0; p5 < 5; ++p5) {
                qv[p5] = __shfl_xor(lv[p5], m, 64);
                qp[p5] = __shfl_xor(lp[p5], m, 64);
            }
            #pragma unroll
            for (int p5 = 0; p5 < 5; ++p5) INS_TIE(lv, lp, qv[p5], qp[p5]);
        }
        if (q == 0) {
            const int rpos = rowBase + (rT>>4)*32 + rf*16 + (rT&15);
            if (rpos < 500) {
                const int pbase = ((grp*4 + ch)*PROWS + rpos)*5;
                #pragma unroll
                for (int p5 = 0; p5 < 5; ++p5) { pV[pbase+p5] = lv[p5]*sc; pP[pbase+p5] = lp[p5]; }
            }
        }
        __syncthreads();
    }
}

// fused merge + edge MLP, 4 threads per src point.
// w1t rows interleaved r=(j&31)*4+(j>>5) — quarters read adjacent rows
// (disjoint bank-quads, conflict-free). b1/W2 folded into row slots 33/34.
__global__ __launch_bounds__(256) void k_edge(const float* __restrict__ X,
        const float* __restrict__ W1, const float* __restrict__ b1,
        const float* __restrict__ W2, const float* __restrict__ b2,
        const float* __restrict__ pV, const int* __restrict__ pP,
        const int* __restrict__ sortedIdx, float* __restrict__ out) {
    __shared__ float w1t[128*36];
    const int tid = threadIdx.x;
    for (int idx = tid; idx < 33*128; idx += 256) {
        int f = idx >> 7, j = idx & 127;
        w1t[((j & 31)*4 + (j >> 5))*36 + f] = W1[idx];
    }
    if (tid < 128) {
        int r = ((tid & 31)*4 + (tid >> 5))*36;
        w1t[r + 33] = b1[tid];
        w1t[r + 34] = W2[tid];
    }
    __syncthreads();
    int rid4 = blockIdx.x*256 + tid;
    if (rid4 >= NGRP*BINSZ*4) return;
    const int rid = rid4 >> 2, quarter = rid4 & 3;
    const int grp = rid / BINSZ;
    const int rowLocal = rid - grp*BINSZ;
    const int b = grp / NBINS, g = grp - b*NBINS;
    // ---- merge 4 ch-partials (duplicated across the 4 quarters; deterministic) ----
    float lv[5]; int lp[5];
    {
        int pbase = (grp*4*PROWS + rowLocal)*5;
        #pragma unroll
        for (int j = 0; j < 5; ++j) { lv[j] = pV[pbase+j]; lp[j] = pP[pbase+j]; }
    }
    #pragma unroll
    for (int chh = 1; chh < 4; ++chh) {
        int pbase = ((grp*4 + chh)*PROWS + rowLocal)*5;
        #pragma unroll
        for (int j = 0; j < 5; ++j) {
            float v = pV[pbase+j]; int p = pP[pbase+j];
            INS_TIE(lv, lp, v, p);
        }
    }
    const int* sIdx = sortedIdx + b*NPTS + g*BINSZ;
    const int src = sIdx[rowLocal];
    int dd[5]; float vv[5];
    #pragma unroll
    for (int j = 0; j < 5; ++j) {
        dd[j] = sIdx[lp[j]];
        vv[j] = 1.f/(1.f + expf(-lv[j]));
    }
    #define CSWAP(i,j) { if (dd[i] > dd[j]) { int td=dd[i];dd[i]=dd[j];dd[j]=td; \
                         float tf=vv[i];vv[i]=vv[j];vv[j]=tf; } }
    CSWAP(0,1) CSWAP(3,4) CSWAP(2,4) CSWAP(2,3) CSWAP(1,4)
    CSWAP(0,3) CSWAP(0,2) CSWAP(1,3) CSWAP(1,2)
    #undef CSWAP
    const int base = b*EDGES_PER_BATCH + src*5;
    if (quarter == 0) {
        #pragma unroll
        for (int e = 0; e < 5; ++e) {
            out[EDGE_TOT   + base + e] = (float)src;
            out[2*EDGE_TOT + base + e] = (float)dd[e];
        }
    }
    // ---- edge MLP over j-range [quarter*32, quarter*32+32) ----
    float4 xs[4];
    {
        const float4* xp = (const float4*)(X + ((size_t)b*NPTS + src)*NFEAT);
        #pragma unroll
        for (int q = 0; q < 4; ++q) xs[q] = xp[q];
    }
    float4 xd[5][4];
    #pragma unroll
    for (int e = 0; e < 5; ++e) {
        const float4* xp = (const float4*)(X + ((size_t)b*NPTS + dd[e])*NFEAT);
        #pragma unroll
        for (int q = 0; q < 4; ++q) xd[e][q] = xp[q];
    }
    float acc[5] = {0.f,0.f,0.f,0.f,0.f};
    for (int jj = 0; jj < 32; ++jj) {       // j = quarter*32 + jj (same order)
        const float* wr = &w1t[(jj*4 + quarter)*36];
        float4 ws0 = ((const float4*)wr)[0];
        float4 ws1 = ((const float4*)wr)[1];
        float4 ws2 = ((const float4*)wr)[2];
        float4 ws3 = ((const float4*)wr)[3];
        float4 u0  = ((const float4*)(wr+16))[0];
        float4 u1  = ((const float4*)(wr+16))[1];
        float4 u2  = ((const float4*)(wr+16))[2];
        float4 u3  = ((const float4*)(wr+16))[3];
        float w32 = wr[32];
        float b1j = wr[33];
        float w2j = wr[34];
        float sh = b1j
            + xs[0].x*ws0.x + xs[0].y*ws0.y + xs[0].z*ws0.z + xs[0].w*ws0.w
            + xs[1].x*ws1.x + xs[1].y*ws1.y + xs[1].z*ws1.z + xs[1].w*ws1.w
            + xs[2].x*ws2.x + xs[2].y*ws2.y + xs[2].z*ws2.z + xs[2].w*ws2.w
            + xs[3].x*ws3.x + xs[3].y*ws3.y + xs[3].z*ws3.z + xs[3].w*ws3.w;
        #pragma unroll
        for (int e = 0; e < 5; ++e) {
            float h = sh
                + xd[e][0].x*u0.x + xd[e][0].y*u0.y + xd[e][0].z*u0.z + xd[e][0].w*u0.w
                + xd[e][1].x*u1.x + xd[e][1].y*u1.y + xd[e][1].z*u1.z + xd[e][1].w*u1.w
                + xd[e][2].x*u2.x + xd[e][2].y*u2.y + xd[e][2].z*u2.z + xd[e][2].w*u2.w
                + xd[e][3].x*u3.x + xd[e][3].y*u3.y + xd[e][3].z*u3.z + xd[e][3].w*u3.w;
            h += vv[e]*w32;
            h = (h > 0.f) ? h : expm1f(h);
            acc[e] += h * w2j;
        }
    }
    // pairwise reduce across the 4 quarters: ((q0+q1)+(q2+q3))
    #pragma unroll
    for (int e = 0; e < 5; ++e) {
        acc[e] += __shfl_xor(acc[e], 1, 64);
        acc[e] += __shfl_xor(acc[e], 2, 64);
    }
    if (quarter != 0) return;
    float b2v = b2[0];
    #pragma unroll
    for (int e = 0; e < 5; ++e) {
        out[base + e] = 1.f/(1.f + expf(-(acc[e] + b2v)));
    }
}

extern "C" void kernel_launch(void* const* d_in, const int* in_sizes, int n_in,
                              void* d_out, int out_size, void* d_ws, size_t ws_size,
                              hipStream_t stream) {
    const float* X   = (const float*)d_in[0];
    const float* We1 = (const float*)d_in[1];
    const float* be1 = (const float*)d_in[2];
    const float* We2 = (const float*)d_in[3];
    const float* be2 = (const float*)d_in[4];
    const float* Wd1 = (const float*)d_in[5];
    const float* bd1 = (const float*)d_in[6];
    const float* Wd2 = (const float*)d_in[7];
    const float* bd2 = (const float*)d_in[8];
    const float* R   = (const float*)d_in[9];
    float* out = (float*)d_out;

    // workspace layout (~54 MB, unchanged footprint):
    // P[row][256] = [Hs|D] occupies exactly the old slab.
    u16* Pw         = (u16*)d_ws;                          // 80000*256 u16
    int*   binIdx   = (int*)(Pw + (size_t)TOTPTS*256);     // 80000
    int*   sortedIdx= binIdx + TOTPTS;                     // 80000
    int*   hist     = sortedIdx + TOTPTS;                  // 160
    float* pV       = (float*)(hist + NBATCH*NBINS);       // 160*4*512*5
    int*   pP       = (int*)(pV + (size_t)NGRP*4*PROWS*5); // 160*4*512*5

    hipMemsetAsync(hist, 0, NBATCH*NBINS*sizeof(int), stream);
    k_enc  <<<TOTPTS/32, 256, 0, stream>>>(X, We1, be1, We2, be2, R, Pw, binIdx, hist);
    k_sort <<<NBATCH*NBINS, 256, 0, stream>>>(binIdx, hist, sortedIdx);
    k_gram <<<NGRP*16, 256, 0, stream>>>(Pw, sortedIdx, pV, pP);
    k_edge <<<(NGRP*BINSZ*4+255)/256, 256, 0, stream>>>(X, Wd1, bd1, Wd2, bd2,
                                                        pV, pP, sortedIdx, out);
}

// Round 11
// 472.929 us; speedup vs baseline: 1.0650x; 1.0650x over previous
//
#include <hip/hip_runtime.h>
#include <cmath>

#define NPTS 10000
#define NBATCH 8
#define NFEAT 16
#define DDIM 128
#define NBINS 20
#define BINSZ 500
#define KSEL 5
#define EDGES_PER_BATCH (NPTS*KSEL)        // 50000
#define EDGE_TOT (NBATCH*EDGES_PER_BATCH)  // 400000
#define TOTPTS (NBATCH*NPTS)               // 80000
#define NGRP (NBATCH*NBINS)                // 160
#define PROWS 512                          // padded rows per (grp,ch) partial slab

typedef _Float16 f16x8 __attribute__((ext_vector_type(8)));
typedef float f32x4 __attribute__((ext_vector_type(4)));
typedef unsigned short u16;
typedef unsigned int u32;

// fp32 -> (Hs, D): Hs = 64*fp16(x), D = fp16((x - fp16(x)) * 64).
// Products then need no runtime scaling:
//   Hs*D = h*l, D*Hs = l*h, Hs*Hs = 4096*h*h ;  S = acc * 2^-12.
static __device__ __forceinline__ void split_f16(float v, u16& hu, u16& du) {
    _Float16 h = (_Float16)v;
    float hf = (float)h;
    if (fabsf(v) < 6.103515625e-05f) { h = (_Float16)0.0f; hf = 0.0f; }
    _Float16 Hs = h * (_Float16)64.0f;              // exact (exponent shift)
    _Float16 D  = (_Float16)((v - hf) * 64.0f);
    hu = __builtin_bit_cast(u16, Hs);
    du = __builtin_bit_cast(u16, D);
}

// enc = ELU(X@W1+b1)@W2+b2, stored as P[row][256] = [Hs(128) | D(128)] f16.
// v11: fused bins KEPT, but restructured per-ep to kill the r10 spill:
// r10 held mul[4][10] (40 regs) + acc (16) live through the whole epilogue;
// allocator budgeted 48 VGPRs -> mul spilled to scratch -> ~1 GB scratch
// traffic -> 260 µs. v11 processes one output point (ep) at a time: pm[10]
// live regs instead of 40, launch_bounds(256,4) gives the allocator a
// 128-reg budget (r5/r8-proven cap). Numerics bit-identical to r10 (same
// products, same shfl-tree masks, same first-max-wins argmax order).
__global__ __launch_bounds__(256, 4) void k_enc(const float* __restrict__ X,
        const float* __restrict__ W1, const float* __restrict__ b1,
        const float* __restrict__ W2, const float* __restrict__ b2,
        const float* __restrict__ R,
        u16* __restrict__ P, int* __restrict__ binIdx, int* __restrict__ hist) {
    __shared__ float hT[128*36];
    __shared__ float Rt[10*128];            // Rt[i][d] = R[d*100+i]
    const int tid = threadIdx.x;
    const int P0 = blockIdx.x * 32;
    for (int idx = tid; idx < 1280; idx += 256) {
        int i = idx >> 7, d = idx & 127;
        Rt[idx] = R[d*100 + i];
    }
    #pragma unroll
    for (int i = 0; i < 16; ++i) {
        int idx = i*256 + tid;
        int p = idx >> 7;
        int j = idx & 127;
        const float* xr = X + (size_t)(P0 + p)*NFEAT;
        float h = b1[j];
        #pragma unroll
        for (int f = 0; f < 16; ++f) h += xr[f] * W1[f*128 + j];
        h = (h > 0.f) ? h : expm1f(h);
        hT[j*36 + p] = h;
    }
    __syncthreads();
    const int jt = tid & 31, pt = tid >> 5;
    const int j0 = jt*4, p0 = pt*4;
    float acc[4][4];
    #pragma unroll
    for (int ep = 0; ep < 4; ++ep)
        #pragma unroll
        for (int ej = 0; ej < 4; ++ej) acc[ep][ej] = b2[j0+ej];
    for (int k = 0; k < 128; ++k) {
        float4 hv = *(const float4*)&hT[k*36 + p0];
        float4 wv = *(const float4*)&W2[k*128 + j0];
        float hvv[4] = {hv.x,hv.y,hv.z,hv.w};
        float wvv[4] = {wv.x,wv.y,wv.z,wv.w};
        #pragma unroll
        for (int ep = 0; ep < 4; ++ep)
            #pragma unroll
            for (int ej = 0; ej < 4; ++ej) acc[ep][ej] += hvv[ep]*wvv[ej];
    }
    // ---- per-ep: bins partial (10 regs), shfl tree, P store, argmax ----
    #pragma unroll
    for (int ep = 0; ep < 4; ++ep) {
        float pm[10];
        #pragma unroll
        for (int i = 0; i < 10; ++i) {
            float4 rv = *(const float4*)&Rt[i*128 + j0];
            pm[i] = acc[ep][0]*rv.x + acc[ep][1]*rv.y
                  + acc[ep][2]*rv.z + acc[ep][3]*rv.w;
        }
        #pragma unroll
        for (int m = 1; m <= 16; m <<= 1)
            #pragma unroll
            for (int i = 0; i < 10; ++i)
                pm[i] += __shfl_xor(pm[i], m, 64);
        {   // store P row ep
            u16 hs[4], ds[4];
            #pragma unroll
            for (int ej = 0; ej < 4; ++ej) split_f16(acc[ep][ej], hs[ej], ds[ej]);
            size_t ro = (size_t)(P0+p0+ep)*256 + j0;
            uint2 hv2, dv2;
            hv2.x = (u32)hs[0] | ((u32)hs[1]<<16); hv2.y = (u32)hs[2] | ((u32)hs[3]<<16);
            dv2.x = (u32)ds[0] | ((u32)ds[1]<<16); dv2.y = (u32)ds[2] | ((u32)ds[3]<<16);
            *(uint2*)&P[ro]       = hv2;
            *(uint2*)&P[ro + 128] = dv2;
        }
        if (jt == 0) {
            float best = pm[0]; int bi = 0;
            #pragma unroll
            for (int i = 1; i < 10; ++i) if (pm[i] > best) { best = pm[i]; bi = i; }
            #pragma unroll
            for (int i = 0; i < 10; ++i) { float v = -pm[i]; if (v > best) { best = v; bi = 10+i; } }
            int gp = P0 + p0 + ep;
            binIdx[gp] = bi;
            atomicAdd(&hist[(gp/NPTS)*NBINS + bi], 1);
        }
    }
}

// stable counting-sort scatter: one block per (batch,bin)
__global__ __launch_bounds__(256) void k_sort(const int* __restrict__ binIdx,
        const int* __restrict__ hist, int* __restrict__ sortedIdx) {
    const int b = blockIdx.x / NBINS;
    const int bin = blockIdx.x % NBINS;
    const int tid = threadIdx.x;
    __shared__ int wtot[4];
    int off = 0;
    for (int k = 0; k < bin; ++k) off += hist[b*NBINS + k];
    const int* bptr = binIdx + b*NPTS;
    int* sptr = sortedIdx + b*NPTS;
    const int lane = tid & 63, wid = tid >> 6;
    for (int c = 0; c < 40; ++c) {
        int i = c*256 + tid;
        bool pred = (i < NPTS) && (bptr[i] == bin);
        unsigned long long mask = __ballot(pred);
        int rank = __popcll(mask & ((1ULL << lane) - 1ULL));
        if (lane == 0) wtot[wid] = __popcll(mask);
        __syncthreads();
        int prefix = 0;
        #pragma unroll
        for (int w = 0; w < 4; ++w) prefix += (w < wid) ? wtot[w] : 0;
        int total = wtot[0]+wtot[1]+wtot[2]+wtot[3];
        if (pred) sptr[off + prefix + rank] = i;
        off += total;
        __syncthreads();
    }
}

// insert (v,p) into sorted-desc 5-list, strict > (candidates arrive ascending p)
#define INS_STRICT(VV,PP,v,p) do { \
  if ((v) > VV[4]) { \
    if ((v) > VV[3]) { VV[4]=VV[3]; PP[4]=PP[3]; \
      if ((v) > VV[2]) { VV[3]=VV[2]; PP[3]=PP[2]; \
        if ((v) > VV[1]) { VV[2]=VV[1]; PP[2]=PP[1]; \
          if ((v) > VV[0]) { VV[1]=VV[0]; PP[1]=PP[0]; VV[0]=(v); PP[0]=(p); } \
          else { VV[1]=(v); PP[1]=(p); } } \
        else { VV[2]=(v); PP[2]=(p); } } \
      else { VV[3]=(v); PP[3]=(p); } } \
    else { VV[4]=(v); PP[4]=(p); } } } while(0)

// tie-aware better-than: (v desc, p asc) — exact lax.top_k semantics
#define BT(va,pa,vb,pb) (((va) > (vb)) || (((va) == (vb)) && ((pa) < (pb))))
#define INS_TIE(VV,PP,v,p) do { \
  if (BT(v,p,VV[4],PP[4])) { \
    if (BT(v,p,VV[3],PP[3])) { VV[4]=VV[3]; PP[4]=PP[3]; \
      if (BT(v,p,VV[2],PP[2])) { VV[3]=VV[2]; PP[3]=PP[2]; \
        if (BT(v,p,VV[1],PP[1])) { VV[2]=VV[1]; PP[2]=PP[1]; \
          if (BT(v,p,VV[0],PP[0])) { VV[1]=VV[0]; PP[1]=PP[0]; VV[0]=(v); PP[0]=(p); } \
          else { VV[1]=(v); PP[1]=(p); } } \
        else { VV[2]=(v); PP[2]=(p); } } \
      else { VV[3]=(v); PP[3]=(p); } } \
    else { VV[4]=(v); PP[4]=(p); } } } while(0)

// Gram via f16 MFMA with pre-scaled split operands (zero runtime scaling):
//   acc = Hs_a·D_b + D_a·Hs_b + Hs_a·Hs_b ;  S = acc·2^-12
// r5-verified structure (94 µs): T[64][132] 2-pass epilogue, LDS 35840,
// launch_bounds(256,4). r6: (256,6) spills acc (750MB scratch). r7: 32-row
// 4-pass epilogue serializes (157µs). r8: A-prefetch neutral — kept.
__global__ __launch_bounds__(256, 4) void k_gram(const u16* __restrict__ P,
        const int* __restrict__ sortedIdx, float* __restrict__ pV, int* __restrict__ pP) {
    __shared__ int gIdx[512];
    __shared__ __align__(16) union ShU {
        struct { u16 H[128][40]; u16 L[128][40]; } bs;   // 20480 B
        float T[64][132];                                // 33792 B
    } sh;
    const int tid = threadIdx.x;
    const int unit = blockIdx.x / 160;      // rowTile*4 + ch
    const int grp  = blockIdx.x - unit*160;
    const int rowTile = unit >> 2, ch = unit & 3;
    const int b = grp / NBINS, g = grp - b*NBINS;
    for (int i = tid; i < 512; i += 256) gIdx[i] = sortedIdx[b*NPTS + g*500 + min(i, 499)];
    __syncthreads();

    const int w    = tid >> 6;              // wave 0..3: rows w*32..w*32+31
    const int lane = tid & 63;
    const int l15  = lane & 15, l4 = lane >> 4;
    const int rowBase = rowTile * 128;

    const size_t ebase = (size_t)b * NPTS * 256;   // halfwords
    const u16* PB = P + ebase;
    const u16* pA0 = PB + (size_t)gIdx[rowBase + w*32 +      l15]*256 + l4*8;
    const u16* pA1 = PB + (size_t)gIdx[rowBase + w*32 + 16 + l15]*256 + l4*8;

    // stager role: thread t copies the 64B ks-chunk of col (t>>1), part (t&1)
    const int scol = tid >> 1, spart = tid & 1;
    const u16* pS = PB + (size_t)gIdx[ch*128 + scol]*256 + spart*128;
    u16* dS = spart ? &sh.bs.L[scol][0] : &sh.bs.H[scol][0];

    f32x4 acc[2][8];
    const f32x4 z4 = {0.f, 0.f, 0.f, 0.f};
    #pragma unroll
    for (int rf = 0; rf < 2; ++rf)
        #pragma unroll
        for (int cf = 0; cf < 8; ++cf) acc[rf][cf] = z4;

    // prologue: stage B regs for ks=0 and A fragments for ks=0
    uint4 s0, s1, s2, s3;
    { const uint4* s = (const uint4*)pS; s0 = s[0]; s1 = s[1]; s2 = s[2]; s3 = s[3]; }
    f16x8 aH0 = *(const f16x8*)(pA0 + 0);
    f16x8 aD0 = *(const f16x8*)(pA0 + 128);
    f16x8 aH1 = *(const f16x8*)(pA1 + 0);
    f16x8 aD1 = *(const f16x8*)(pA1 + 128);

    #pragma unroll
    for (int ks = 0; ks < 4; ++ks) {
        __syncthreads();                    // prior k-step's LDS reads done
        {   // write staged B regs (data already in flight / in regs)
            uint4* d = (uint4*)dS;
            d[0] = s0; d[1] = s1; d[2] = s2; d[3] = s3;
        }
        if (ks < 3) {                       // prefetch next B chunk under MFMA
            const uint4* s = (const uint4*)(pS + (ks+1)*32);
            s0 = s[0]; s1 = s[1]; s2 = s[2]; s3 = s[3];
        }
        __syncthreads();                    // staged data visible
        #pragma unroll
        for (int cf = 0; cf < 8; ++cf) {
            const int col = cf*16 + l15;
            const f16x8 bH = *(const f16x8*)&sh.bs.H[col][l4*8];
            const f16x8 bD = *(const f16x8*)&sh.bs.L[col][l4*8];
            acc[0][cf] = __builtin_amdgcn_mfma_f32_16x16x32_f16(aH0, bD, acc[0][cf], 0, 0, 0);
            acc[1][cf] = __builtin_amdgcn_mfma_f32_16x16x32_f16(aH1, bD, acc[1][cf], 0, 0, 0);
            acc[0][cf] = __builtin_amdgcn_mfma_f32_16x16x32_f16(aD0, bH, acc[0][cf], 0, 0, 0);
            acc[1][cf] = __builtin_amdgcn_mfma_f32_16x16x32_f16(aD1, bH, acc[1][cf], 0, 0, 0);
            acc[0][cf] = __builtin_amdgcn_mfma_f32_16x16x32_f16(aH0, bH, acc[0][cf], 0, 0, 0);
            acc[1][cf] = __builtin_amdgcn_mfma_f32_16x16x32_f16(aH1, bH, acc[1][cf], 0, 0, 0);
        }
        if (ks < 3) {                       // prefetch A for ks+1
            const int oH = (ks+1)*32;
            const int oD = 128 + (ks+1)*32;
            aH0 = *(const f16x8*)(pA0 + oH);
            aD0 = *(const f16x8*)(pA0 + oD);
            aH1 = *(const f16x8*)(pA1 + oH);
            aD1 = *(const f16x8*)(pA1 + oD);
        }
    }
    __syncthreads();                        // k-loop LDS reads done; reuse as T

    // ---- epilogue: per rf-half, LDS transpose then 4-thread/row top-5 ----
    const float sc = 2.44140625e-4f;        // 2^-12, applied to survivors only
    const int rT = tid >> 2;                // 0..63: T-row this thread reduces
    const int q  = tid & 3;                 // chunk interleave c4 = 4t+q
    const bool chk = (ch == 3);             // chunks >= 29 invalid when ch==3
    #pragma unroll
    for (int rf = 0; rf < 2; ++rf) {
        #pragma unroll
        for (int cf = 0; cf < 8; ++cf) {
            const int col = cf*16 + l15;
            const int r0  = w*16 + l4*4;
            #pragma unroll
            for (int j = 0; j < 4; ++j) sh.T[r0+j][col] = acc[rf][cf][j];
        }
        __syncthreads();
        float lv[5]; int lp[5];
        #pragma unroll
        for (int p5 = 0; p5 < 5; ++p5) { lv[p5] = -3.4e38f; lp[p5] = 0x7fffffff; }
        const float* Tr = &sh.T[rT][0];
        #pragma unroll
        for (int t = 0; t < 8; ++t) {
            const int c4 = t*4 + q;         // ascending cpos per thread
            if (!chk || c4 < 29) {          // 116 valid cols = chunks 0..28
                float4 v4 = *(const float4*)&Tr[c4*4];
                float vv4[4] = {v4.x, v4.y, v4.z, v4.w};
                #pragma unroll
                for (int e = 0; e < 4; ++e)
                    INS_STRICT(lv, lp, vv4[e], ch*128 + c4*4 + e);
            }
        }
        #pragma unroll
        for (int m = 1; m < 4; m <<= 1) {
            float qv[5]; int qp[5];
            #pragma unroll
            for (int p5 = 0; p5 < 5; ++p5) {
                qv[p5] = __shfl_xor(lv[p5], m, 64);
                qp[p5] = __shfl_xor(lp[p5], m, 64);
            }
            #pragma unroll
            for (int p5 = 0; p5 < 5; ++p5) INS_TIE(lv, lp, qv[p5], qp[p5]);
        }
        if (q == 0) {
            const int rpos = rowBase + (rT>>4)*32 + rf*16 + (rT&15);
            if (rpos < 500) {
                const int pbase = ((grp*4 + ch)*PROWS + rpos)*5;
                #pragma unroll
                for (int p5 = 0; p5 < 5; ++p5) { pV[pbase+p5] = lv[p5]*sc; pP[pbase+p5] = lp[p5]; }
            }
        }
        __syncthreads();
    }
}

// fused merge + edge MLP, 4 threads per src point.
// w1t rows interleaved r=(j&31)*4+(j>>5) — quarters read adjacent rows
// (disjoint bank-quads, conflict-free). b1/W2 folded into row slots 33/34.
__global__ __launch_bounds__(256) void k_edge(const float* __restrict__ X,
        const float* __restrict__ W1, const float* __restrict__ b1,
        const float* __restrict__ W2, const float* __restrict__ b2,
        const float* __restrict__ pV, const int* __restrict__ pP,
        const int* __restrict__ sortedIdx, float* __restrict__ out) {
    __shared__ float w1t[128*36];
    const int tid = threadIdx.x;
    for (int idx = tid; idx < 33*128; idx += 256) {
        int f = idx >> 7, j = idx & 127;
        w1t[((j & 31)*4 + (j >> 5))*36 + f] = W1[idx];
    }
    if (tid < 128) {
        int r = ((tid & 31)*4 + (tid >> 5))*36;
        w1t[r + 33] = b1[tid];
        w1t[r + 34] = W2[tid];
    }
    __syncthreads();
    int rid4 = blockIdx.x*256 + tid;
    if (rid4 >= NGRP*BINSZ*4) return;
    const int rid = rid4 >> 2, quarter = rid4 & 3;
    const int grp = rid / BINSZ;
    const int rowLocal = rid - grp*BINSZ;
    const int b = grp / NBINS, g = grp - b*NBINS;
    // ---- merge 4 ch-partials (duplicated across the 4 quarters; deterministic) ----
    float lv[5]; int lp[5];
    {
        int pbase = (grp*4*PROWS + rowLocal)*5;
        #pragma unroll
        for (int j = 0; j < 5; ++j) { lv[j] = pV[pbase+j]; lp[j] = pP[pbase+j]; }
    }
    #pragma unroll
    for (int chh = 1; chh < 4; ++chh) {
        int pbase = ((grp*4 + chh)*PROWS + rowLocal)*5;
        #pragma unroll
        for (int j = 0; j < 5; ++j) {
            float v = pV[pbase+j]; int p = pP[pbase+j];
            INS_TIE(lv, lp, v, p);
        }
    }
    const int* sIdx = sortedIdx + b*NPTS + g*BINSZ;
    const int src = sIdx[rowLocal];
    int dd[5]; float vv[5];
    #pragma unroll
    for (int j = 0; j < 5; ++j) {
        dd[j] = sIdx[lp[j]];
        vv[j] = 1.f/(1.f + expf(-lv[j]));
    }
    #define CSWAP(i,j) { if (dd[i] > dd[j]) { int td=dd[i];dd[i]=dd[j];dd[j]=td; \
                         float tf=vv[i];vv[i]=vv[j];vv[j]=tf; } }
    CSWAP(0,1) CSWAP(3,4) CSWAP(2,4) CSWAP(2,3) CSWAP(1,4)
    CSWAP(0,3) CSWAP(0,2) CSWAP(1,3) CSWAP(1,2)
    #undef CSWAP
    const int base = b*EDGES_PER_BATCH + src*5;
    if (quarter == 0) {
        #pragma unroll
        for (int e = 0; e < 5; ++e) {
            out[EDGE_TOT   + base + e] = (float)src;
            out[2*EDGE_TOT + base + e] = (float)dd[e];
        }
    }
    // ---- edge MLP over j-range [quarter*32, quarter*32+32) ----
    float4 xs[4];
    {
        const float4* xp = (const float4*)(X + ((size_t)b*NPTS + src)*NFEAT);
        #pragma unroll
        for (int q = 0; q < 4; ++q) xs[q] = xp[q];
    }
    float4 xd[5][4];
    #pragma unroll
    for (int e = 0; e < 5; ++e) {
        const float4* xp = (const float4*)(X + ((size_t)b*NPTS + dd[e])*NFEAT);
        #pragma unroll
        for (int q = 0; q < 4; ++q) xd[e][q] = xp[q];
    }
    float acc[5] = {0.f,0.f,0.f,0.f,0.f};
    for (int jj = 0; jj < 32; ++jj) {       // j = quarter*32 + jj (same order)
        const float* wr = &w1t[(jj*4 + quarter)*36];
        float4 ws0 = ((const float4*)wr)[0];
        float4 ws1 = ((const float4*)wr)[1];
        float4 ws2 = ((const float4*)wr)[2];
        float4 ws3 = ((const float4*)wr)[3];
        float4 u0  = ((const float4*)(wr+16))[0];
        float4 u1  = ((const float4*)(wr+16))[1];
        float4 u2  = ((const float4*)(wr+16))[2];
        float4 u3  = ((const float4*)(wr+16))[3];
        float w32 = wr[32];
        float b1j = wr[33];
        float w2j = wr[34];
        float sh = b1j
            + xs[0].x*ws0.x + xs[0].y*ws0.y + xs[0].z*ws0.z + xs[0].w*ws0.w
            + xs[1].x*ws1.x + xs[1].y*ws1.y + xs[1].z*ws1.z + xs[1].w*ws1.w
            + xs[2].x*ws2.x + xs[2].y*ws2.y + xs[2].z*ws2.z + xs[2].w*ws2.w
            + xs[3].x*ws3.x + xs[3].y*ws3.y + xs[3].z*ws3.z + xs[3].w*ws3.w;
        #pragma unroll
        for (int e = 0; e < 5; ++e) {
            float h = sh
                + xd[e][0].x*u0.x + xd[e][0].y*u0.y + xd[e][0].z*u0.z + xd[e][0].w*u0.w
                + xd[e][1].x*u1.x + xd[e][1].y*u1.y + xd[e][1].z*u1.z + xd[e][1].w*u1.w
                + xd[e][2].x*u2.x + xd[e][2].y*u2.y + xd[e][2].z*u2.z + xd[e][2].w*u2.w
                + xd[e][3].x*u3.x + xd[e][3].y*u3.y + xd[e][3].z*u3.z + xd[e][3].w*u3.w;
            h += vv[e]*w32;
            h = (h > 0.f) ? h : expm1f(h);
            acc[e] += h * w2j;
        }
    }
    // pairwise reduce across the 4 quarters: ((q0+q1)+(q2+q3))
    #pragma unroll
    for (int e = 0; e < 5; ++e) {
        acc[e] += __shfl_xor(acc[e], 1, 64);
        acc[e] += __shfl_xor(acc[e], 2, 64);
    }
    if (quarter != 0) return;
    float b2v = b2[0];
    #pragma unroll
    for (int e = 0; e < 5; ++e) {
        out[base + e] = 1.f/(1.f + expf(-(acc[e] + b2v)));
    }
}

extern "C" void kernel_launch(void* const* d_in, const int* in_sizes, int n_in,
                              void* d_out, int out_size, void* d_ws, size_t ws_size,
                              hipStream_t stream) {
    const float* X   = (const float*)d_in[0];
    const float* We1 = (const float*)d_in[1];
    const float* be1 = (const float*)d_in[2];
    const float* We2 = (const float*)d_in[3];
    const float* be2 = (const float*)d_in[4];
    const float* Wd1 = (const float*)d_in[5];
    const float* bd1 = (const float*)d_in[6];
    const float* Wd2 = (const float*)d_in[7];
    const float* bd2 = (const float*)d_in[8];
    const float* R   = (const float*)d_in[9];
    float* out = (float*)d_out;

    // workspace layout (~54 MB, unchanged footprint):
    // P[row][256] = [Hs|D] occupies exactly the old slab.
    u16* Pw         = (u16*)d_ws;                          // 80000*256 u16
    int*   binIdx   = (int*)(Pw + (size_t)TOTPTS*256);     // 80000
    int*   sortedIdx= binIdx + TOTPTS;                     // 80000
    int*   hist     = sortedIdx + TOTPTS;                  // 160
    float* pV       = (float*)(hist + NBATCH*NBINS);       // 160*4*512*5
    int*   pP       = (int*)(pV + (size_t)NGRP*4*PROWS*5); // 160*4*512*5

    hipMemsetAsync(hist, 0, NBATCH*NBINS*sizeof(int), stream);
    k_enc  <<<TOTPTS/32, 256, 0, stream>>>(X, We1, be1, We2, be2, R, Pw, binIdx, hist);
    k_sort <<<NBATCH*NBINS, 256, 0, stream>>>(binIdx, hist, sortedIdx);
    k_gram <<<NGRP*16, 256, 0, stream>>>(Pw, sortedIdx, pV, pP);
    k_edge <<<(NGRP*BINSZ*4+255)/256, 256, 0, stream>>>(X, Wd1, bd1, Wd2, bd2,
                                                        pV, pP, sortedIdx, out);
}

// Round 12
// 406.610 us; speedup vs baseline: 1.2388x; 1.1631x over previous
//
#include <hip/hip_runtime.h>
#include <cmath>

#define NPTS 10000
#define NBATCH 8
#define NFEAT 16
#define DDIM 128
#define NBINS 20
#define BINSZ 500
#define KSEL 5
#define EDGES_PER_BATCH (NPTS*KSEL)        // 50000
#define EDGE_TOT (NBATCH*EDGES_PER_BATCH)  // 400000
#define TOTPTS (NBATCH*NPTS)               // 80000
#define NGRP (NBATCH*NBINS)                // 160
#define PROWS 512                          // padded rows per (grp,ch) partial slab

typedef _Float16 f16x8 __attribute__((ext_vector_type(8)));
typedef float f32x4 __attribute__((ext_vector_type(4)));
typedef unsigned short u16;
typedef unsigned int u32;

// fp32 -> (Hs, D): Hs = 64*fp16(x), D = fp16((x - fp16(x)) * 64).
// Products then need no runtime scaling:
//   Hs*D = h*l, D*Hs = l*h, Hs*Hs = 4096*h*h ;  S = acc * 2^-12.
static __device__ __forceinline__ void split_f16(float v, u16& hu, u16& du) {
    _Float16 h = (_Float16)v;
    float hf = (float)h;
    if (fabsf(v) < 6.103515625e-05f) { h = (_Float16)0.0f; hf = 0.0f; }
    _Float16 Hs = h * (_Float16)64.0f;              // exact (exponent shift)
    _Float16 D  = (_Float16)((v - hf) * 64.0f);
    hu = __builtin_bit_cast(u16, Hs);
    du = __builtin_bit_cast(u16, D);
}

static __device__ __forceinline__ float f16bits(u16 u) {
    return (float)__builtin_bit_cast(_Float16, u);
}

// enc = ELU(X@W1+b1)@W2+b2, stored as P[row][256] = [Hs(128) | D(128)] f16.
// Block 0 also zeroes the bin histogram (k_bins runs after k_enc completes).
// NOTE (r10/r11): fusing the bins projection into this kernel was tried twice
// and regressed 2.3-2.6x — the allocator compiles the fused epilogue at
// 40-48 VGPRs (occupancy heuristic), which either spills mul[] (r10, 1 GB
// scratch) or starves the k-loop of load ILP (r11, VALUBusy 21%). Split wins.
__global__ __launch_bounds__(256) void k_enc(const float* __restrict__ X,
        const float* __restrict__ W1, const float* __restrict__ b1,
        const float* __restrict__ W2, const float* __restrict__ b2,
        u16* __restrict__ P, int* __restrict__ hist) {
    __shared__ float hT[128*36];
    const int tid = threadIdx.x;
    const int P0 = blockIdx.x * 32;
    if (blockIdx.x == 0 && tid < NBATCH*NBINS) hist[tid] = 0;
    #pragma unroll
    for (int i = 0; i < 16; ++i) {
        int idx = i*256 + tid;
        int p = idx >> 7;
        int j = idx & 127;
        const float* xr = X + (size_t)(P0 + p)*NFEAT;
        float h = b1[j];
        #pragma unroll
        for (int f = 0; f < 16; ++f) h += xr[f] * W1[f*128 + j];
        h = (h > 0.f) ? h : expm1f(h);
        hT[j*36 + p] = h;
    }
    __syncthreads();
    const int jt = tid & 31, pt = tid >> 5;
    const int j0 = jt*4, p0 = pt*4;
    float acc[4][4];
    #pragma unroll
    for (int ep = 0; ep < 4; ++ep)
        #pragma unroll
        for (int ej = 0; ej < 4; ++ej) acc[ep][ej] = b2[j0+ej];
    for (int k = 0; k < 128; ++k) {
        float4 hv = *(const float4*)&hT[k*36 + p0];
        float4 wv = *(const float4*)&W2[k*128 + j0];
        float hvv[4] = {hv.x,hv.y,hv.z,hv.w};
        float wvv[4] = {wv.x,wv.y,wv.z,wv.w};
        #pragma unroll
        for (int ep = 0; ep < 4; ++ep)
            #pragma unroll
            for (int ej = 0; ej < 4; ++ej) acc[ep][ej] += hvv[ep]*wvv[ej];
    }
    #pragma unroll
    for (int ep = 0; ep < 4; ++ep) {
        u16 hs[4], ds[4];
        #pragma unroll
        for (int ej = 0; ej < 4; ++ej) split_f16(acc[ep][ej], hs[ej], ds[ej]);
        size_t ro = (size_t)(P0+p0+ep)*256 + j0;
        uint2 hv2, dv2;
        hv2.x = (u32)hs[0] | ((u32)hs[1]<<16); hv2.y = (u32)hs[2] | ((u32)hs[3]<<16);
        dv2.x = (u32)ds[0] | ((u32)ds[1]<<16); dv2.y = (u32)ds[2] | ((u32)ds[3]<<16);
        *(uint2*)&P[ro]       = hv2;
        *(uint2*)&P[ro + 128] = dv2;
    }
}

// mul = enc @ R[:, :10]; bin = argmax([mul, -mul]) first-max-wins; histogram.
// Uses x' = Hs + D = 64*x — argmax invariant to the positive scale.
// 4 threads/point; Rl rows interleaved (d&31)*4+(d>>5) — conflict-free.
__global__ __launch_bounds__(256) void k_bins(const u16* __restrict__ P,
        const float* __restrict__ R,
        int* __restrict__ binIdx, int* __restrict__ hist) {
    __shared__ float Rl[1280];
    const int tid = threadIdx.x;
    for (int idx = tid; idx < 1280; idx += 256) {
        int d = idx / 10, i = idx - d*10;
        int row = (d & 31)*4 + (d >> 5);
        Rl[row*10 + i] = R[d*100 + i];
    }
    __syncthreads();
    const int gp4 = blockIdx.x*256 + tid;    // grid sized exactly: TOTPTS*4
    const int point = gp4 >> 2, seg = gp4 & 3;
    float acc[10];
    #pragma unroll
    for (int i = 0; i < 10; ++i) acc[i] = 0.f;
    const uint4* hr = (const uint4*)(P + (size_t)point*256 + seg*32);
    const uint4* lr = (const uint4*)(P + (size_t)point*256 + 128 + seg*32);
    #pragma unroll
    for (int c = 0; c < 4; ++c) {
        uint4 hv = hr[c], lv = lr[c];
        float x[8];
        x[0] = f16bits((u16)(hv.x & 0xffff)) + f16bits((u16)(lv.x & 0xffff));
        x[1] = f16bits((u16)(hv.x >> 16))    + f16bits((u16)(lv.x >> 16));
        x[2] = f16bits((u16)(hv.y & 0xffff)) + f16bits((u16)(lv.y & 0xffff));
        x[3] = f16bits((u16)(hv.y >> 16))    + f16bits((u16)(lv.y >> 16));
        x[4] = f16bits((u16)(hv.z & 0xffff)) + f16bits((u16)(lv.z & 0xffff));
        x[5] = f16bits((u16)(hv.z >> 16))    + f16bits((u16)(lv.z >> 16));
        x[6] = f16bits((u16)(hv.w & 0xffff)) + f16bits((u16)(lv.w & 0xffff));
        x[7] = f16bits((u16)(hv.w >> 16))    + f16bits((u16)(lv.w >> 16));
        #pragma unroll
        for (int e = 0; e < 8; ++e) {
            const float* rr = &Rl[((c*8 + e)*4 + seg)*10];
            #pragma unroll
            for (int i = 0; i < 10; ++i) acc[i] += x[e]*rr[i];
        }
    }
    // combine the 4 seg-partials (lanes 4k..4k+3)
    #pragma unroll
    for (int i = 0; i < 10; ++i) {
        acc[i] += __shfl_xor(acc[i], 1, 64);
        acc[i] += __shfl_xor(acc[i], 2, 64);
    }
    if (seg != 0) return;
    float best = acc[0]; int bi = 0;
    #pragma unroll
    for (int i = 1; i < 10; ++i) if (acc[i] > best) { best = acc[i]; bi = i; }
    #pragma unroll
    for (int i = 0; i < 10; ++i) { float v = -acc[i]; if (v > best) { best = v; bi = 10+i; } }
    binIdx[point] = bi;
    atomicAdd(&hist[(point/NPTS)*NBINS + bi], 1);
}

// stable counting-sort scatter: one block per (batch,bin)
__global__ __launch_bounds__(256) void k_sort(const int* __restrict__ binIdx,
        const int* __restrict__ hist, int* __restrict__ sortedIdx) {
    const int b = blockIdx.x / NBINS;
    const int bin = blockIdx.x % NBINS;
    const int tid = threadIdx.x;
    __shared__ int wtot[4];
    int off = 0;
    for (int k = 0; k < bin; ++k) off += hist[b*NBINS + k];
    const int* bptr = binIdx + b*NPTS;
    int* sptr = sortedIdx + b*NPTS;
    const int lane = tid & 63, wid = tid >> 6;
    for (int c = 0; c < 40; ++c) {
        int i = c*256 + tid;
        bool pred = (i < NPTS) && (bptr[i] == bin);
        unsigned long long mask = __ballot(pred);
        int rank = __popcll(mask & ((1ULL << lane) - 1ULL));
        if (lane == 0) wtot[wid] = __popcll(mask);
        __syncthreads();
        int prefix = 0;
        #pragma unroll
        for (int w = 0; w < 4; ++w) prefix += (w < wid) ? wtot[w] : 0;
        int total = wtot[0]+wtot[1]+wtot[2]+wtot[3];
        if (pred) sptr[off + prefix + rank] = i;
        off += total;
        __syncthreads();
    }
}

// insert (v,p) into sorted-desc 5-list, strict > (candidates arrive ascending p)
#define INS_STRICT(VV,PP,v,p) do { \
  if ((v) > VV[4]) { \
    if ((v) > VV[3]) { VV[4]=VV[3]; PP[4]=PP[3]; \
      if ((v) > VV[2]) { VV[3]=VV[2]; PP[3]=PP[2]; \
        if ((v) > VV[1]) { VV[2]=VV[1]; PP[2]=PP[1]; \
          if ((v) > VV[0]) { VV[1]=VV[0]; PP[1]=PP[0]; VV[0]=(v); PP[0]=(p); } \
          else { VV[1]=(v); PP[1]=(p); } } \
        else { VV[2]=(v); PP[2]=(p); } } \
      else { VV[3]=(v); PP[3]=(p); } } \
    else { VV[4]=(v); PP[4]=(p); } } } while(0)

// tie-aware better-than: (v desc, p asc) — exact lax.top_k semantics
#define BT(va,pa,vb,pb) (((va) > (vb)) || (((va) == (vb)) && ((pa) < (pb))))
#define INS_TIE(VV,PP,v,p) do { \
  if (BT(v,p,VV[4],PP[4])) { \
    if (BT(v,p,VV[3],PP[3])) { VV[4]=VV[3]; PP[4]=PP[3]; \
      if (BT(v,p,VV[2],PP[2])) { VV[3]=VV[2]; PP[3]=PP[2]; \
        if (BT(v,p,VV[1],PP[1])) { VV[2]=VV[1]; PP[2]=PP[1]; \
          if (BT(v,p,VV[0],PP[0])) { VV[1]=VV[0]; PP[1]=PP[0]; VV[0]=(v); PP[0]=(p); } \
          else { VV[1]=(v); PP[1]=(p); } } \
        else { VV[2]=(v); PP[2]=(p); } } \
      else { VV[3]=(v); PP[3]=(p); } } \
    else { VV[4]=(v); PP[4]=(p); } } } while(0)

// Gram via f16 MFMA with pre-scaled split operands (zero runtime scaling):
//   acc = Hs_a·D_b + D_a·Hs_b + Hs_a·Hs_b ;  S = acc·2^-12
// r5-verified structure (94 µs): T[64][132] 2-pass epilogue, LDS 35840,
// launch_bounds(256,4). r6: (256,6) spills acc (750MB scratch). r7: 32-row
// 4-pass epilogue serializes (157µs). r8: A-prefetch neutral — kept.
__global__ __launch_bounds__(256, 4) void k_gram(const u16* __restrict__ P,
        const int* __restrict__ sortedIdx, float* __restrict__ pV, int* __restrict__ pP) {
    __shared__ int gIdx[512];
    __shared__ __align__(16) union ShU {
        struct { u16 H[128][40]; u16 L[128][40]; } bs;   // 20480 B
        float T[64][132];                                // 33792 B
    } sh;
    const int tid = threadIdx.x;
    const int unit = blockIdx.x / 160;      // rowTile*4 + ch
    const int grp  = blockIdx.x - unit*160;
    const int rowTile = unit >> 2, ch = unit & 3;
    const int b = grp / NBINS, g = grp - b*NBINS;
    for (int i = tid; i < 512; i += 256) gIdx[i] = sortedIdx[b*NPTS + g*500 + min(i, 499)];
    __syncthreads();

    const int w    = tid >> 6;              // wave 0..3: rows w*32..w*32+31
    const int lane = tid & 63;
    const int l15  = lane & 15, l4 = lane >> 4;
    const int rowBase = rowTile * 128;

    const size_t ebase = (size_t)b * NPTS * 256;   // halfwords
    const u16* PB = P + ebase;
    const u16* pA0 = PB + (size_t)gIdx[rowBase + w*32 +      l15]*256 + l4*8;
    const u16* pA1 = PB + (size_t)gIdx[rowBase + w*32 + 16 + l15]*256 + l4*8;

    // stager role: thread t copies the 64B ks-chunk of col (t>>1), part (t&1)
    const int scol = tid >> 1, spart = tid & 1;
    const u16* pS = PB + (size_t)gIdx[ch*128 + scol]*256 + spart*128;
    u16* dS = spart ? &sh.bs.L[scol][0] : &sh.bs.H[scol][0];

    f32x4 acc[2][8];
    const f32x4 z4 = {0.f, 0.f, 0.f, 0.f};
    #pragma unroll
    for (int rf = 0; rf < 2; ++rf)
        #pragma unroll
        for (int cf = 0; cf < 8; ++cf) acc[rf][cf] = z4;

    // prologue: stage B regs for ks=0 and A fragments for ks=0
    uint4 s0, s1, s2, s3;
    { const uint4* s = (const uint4*)pS; s0 = s[0]; s1 = s[1]; s2 = s[2]; s3 = s[3]; }
    f16x8 aH0 = *(const f16x8*)(pA0 + 0);
    f16x8 aD0 = *(const f16x8*)(pA0 + 128);
    f16x8 aH1 = *(const f16x8*)(pA1 + 0);
    f16x8 aD1 = *(const f16x8*)(pA1 + 128);

    #pragma unroll
    for (int ks = 0; ks < 4; ++ks) {
        __syncthreads();                    // prior k-step's LDS reads done
        {   // write staged B regs (data already in flight / in regs)
            uint4* d = (uint4*)dS;
            d[0] = s0; d[1] = s1; d[2] = s2; d[3] = s3;
        }
        if (ks < 3) {                       // prefetch next B chunk under MFMA
            const uint4* s = (const uint4*)(pS + (ks+1)*32);
            s0 = s[0]; s1 = s[1]; s2 = s[2]; s3 = s[3];
        }
        __syncthreads();                    // staged data visible
        #pragma unroll
        for (int cf = 0; cf < 8; ++cf) {
            const int col = cf*16 + l15;
            const f16x8 bH = *(const f16x8*)&sh.bs.H[col][l4*8];
            const f16x8 bD = *(const f16x8*)&sh.bs.L[col][l4*8];
            acc[0][cf] = __builtin_amdgcn_mfma_f32_16x16x32_f16(aH0, bD, acc[0][cf], 0, 0, 0);
            acc[1][cf] = __builtin_amdgcn_mfma_f32_16x16x32_f16(aH1, bD, acc[1][cf], 0, 0, 0);
            acc[0][cf] = __builtin_amdgcn_mfma_f32_16x16x32_f16(aD0, bH, acc[0][cf], 0, 0, 0);
            acc[1][cf] = __builtin_amdgcn_mfma_f32_16x16x32_f16(aD1, bH, acc[1][cf], 0, 0, 0);
            acc[0][cf] = __builtin_amdgcn_mfma_f32_16x16x32_f16(aH0, bH, acc[0][cf], 0, 0, 0);
            acc[1][cf] = __builtin_amdgcn_mfma_f32_16x16x32_f16(aH1, bH, acc[1][cf], 0, 0, 0);
        }
        if (ks < 3) {                       // prefetch A for ks+1
            const int oH = (ks+1)*32;
            const int oD = 128 + (ks+1)*32;
            aH0 = *(const f16x8*)(pA0 + oH);
            aD0 = *(const f16x8*)(pA0 + oD);
            aH1 = *(const f16x8*)(pA1 + oH);
            aD1 = *(const f16x8*)(pA1 + oD);
        }
    }
    __syncthreads();                        // k-loop LDS reads done; reuse as T

    // ---- epilogue: per rf-half, LDS transpose then 4-thread/row top-5 ----
    const float sc = 2.44140625e-4f;        // 2^-12, applied to survivors only
    const int rT = tid >> 2;                // 0..63: T-row this thread reduces
    const int q  = tid & 3;                 // chunk interleave c4 = 4t+q
    const bool chk = (ch == 3);             // chunks >= 29 invalid when ch==3
    #pragma unroll
    for (int rf = 0; rf < 2; ++rf) {
        #pragma unroll
        for (int cf = 0; cf < 8; ++cf) {
            const int col = cf*16 + l15;
            const int r0  = w*16 + l4*4;
            #pragma unroll
            for (int j = 0; j < 4; ++j) sh.T[r0+j][col] = acc[rf][cf][j];
        }
        __syncthreads();
        float lv[5]; int lp[5];
        #pragma unroll
        for (int p5 = 0; p5 < 5; ++p5) { lv[p5] = -3.4e38f; lp[p5] = 0x7fffffff; }
        const float* Tr = &sh.T[rT][0];
        #pragma unroll
        for (int t = 0; t < 8; ++t) {
            const int c4 = t*4 + q;         // ascending cpos per thread
            if (!chk || c4 < 29) {          // 116 valid cols = chunks 0..28
                float4 v4 = *(const float4*)&Tr[c4*4];
                float vv4[4] = {v4.x, v4.y, v4.z, v4.w};
                #pragma unroll
                for (int e = 0; e < 4; ++e)
                    INS_STRICT(lv, lp, vv4[e], ch*128 + c4*4 + e);
            }
        }
        #pragma unroll
        for (int m = 1; m < 4; m <<= 1) {
            float qv[5]; int qp[5];
            #pragma unroll
            for (int p5 = 0; p5 < 5; ++p5) {
                qv[p5] = __shfl_xor(lv[p5], m, 64);
                qp[p5] = __shfl_xor(lp[p5], m, 64);
            }
            #pragma unroll
            for (int p5 = 0; p5 < 5; ++p5) INS_TIE(lv, lp, qv[p5], qp[p5]);
        }
        if (q == 0) {
            const int rpos = rowBase + (rT>>4)*32 + rf*16 + (rT&15);
            if (rpos < 500) {
                const int pbase = ((grp*4 + ch)*PROWS + rpos)*5;
                #pragma unroll
                for (int p5 = 0; p5 < 5; ++p5) { pV[pbase+p5] = lv[p5]*sc; pP[pbase+p5] = lp[p5]; }
            }
        }
        __syncthreads();
    }
}

// fused merge + edge MLP, 4 threads per src point.
// w1t rows interleaved r=(j&31)*4+(j>>5) — quarters read adjacent rows
// (disjoint bank-quads, conflict-free). b1/W2 folded into row slots 33/34.
__global__ __launch_bounds__(256) void k_edge(const float* __restrict__ X,
        const float* __restrict__ W1, const float* __restrict__ b1,
        const float* __restrict__ W2, const float* __restrict__ b2,
        const float* __restrict__ pV, const int* __restrict__ pP,
        const int* __restrict__ sortedIdx, float* __restrict__ out) {
    __shared__ float w1t[128*36];
    const int tid = threadIdx.x;
    for (int idx = tid; idx < 33*128; idx += 256) {
        int f = idx >> 7, j = idx & 127;
        w1t[((j & 31)*4 + (j >> 5))*36 + f] = W1[idx];
    }
    if (tid < 128) {
        int r = ((tid & 31)*4 + (tid >> 5))*36;
        w1t[r + 33] = b1[tid];
        w1t[r + 34] = W2[tid];
    }
    __syncthreads();
    int rid4 = blockIdx.x*256 + tid;
    if (rid4 >= NGRP*BINSZ*4) return;
    const int rid = rid4 >> 2, quarter = rid4 & 3;
    const int grp = rid / BINSZ;
    const int rowLocal = rid - grp*BINSZ;
    const int b = grp / NBINS, g = grp - b*NBINS;
    // ---- merge 4 ch-partials (duplicated across the 4 quarters; deterministic) ----
    float lv[5]; int lp[5];
    {
        int pbase = (grp*4*PROWS + rowLocal)*5;
        #pragma unroll
        for (int j = 0; j < 5; ++j) { lv[j] = pV[pbase+j]; lp[j] = pP[pbase+j]; }
    }
    #pragma unroll
    for (int chh = 1; chh < 4; ++chh) {
        int pbase = ((grp*4 + chh)*PROWS + rowLocal)*5;
        #pragma unroll
        for (int j = 0; j < 5; ++j) {
            float v = pV[pbase+j]; int p = pP[pbase+j];
            INS_TIE(lv, lp, v, p);
        }
    }
    const int* sIdx = sortedIdx + b*NPTS + g*BINSZ;
    const int src = sIdx[rowLocal];
    int dd[5]; float vv[5];
    #pragma unroll
    for (int j = 0; j < 5; ++j) {
        dd[j] = sIdx[lp[j]];
        vv[j] = 1.f/(1.f + expf(-lv[j]));
    }
    #define CSWAP(i,j) { if (dd[i] > dd[j]) { int td=dd[i];dd[i]=dd[j];dd[j]=td; \
                         float tf=vv[i];vv[i]=vv[j];vv[j]=tf; } }
    CSWAP(0,1) CSWAP(3,4) CSWAP(2,4) CSWAP(2,3) CSWAP(1,4)
    CSWAP(0,3) CSWAP(0,2) CSWAP(1,3) CSWAP(1,2)
    #undef CSWAP
    const int base = b*EDGES_PER_BATCH + src*5;
    if (quarter == 0) {
        #pragma unroll
        for (int e = 0; e < 5; ++e) {
            out[EDGE_TOT   + base + e] = (float)src;
            out[2*EDGE_TOT + base + e] = (float)dd[e];
        }
    }
    // ---- edge MLP over j-range [quarter*32, quarter*32+32) ----
    float4 xs[4];
    {
        const float4* xp = (const float4*)(X + ((size_t)b*NPTS + src)*NFEAT);
        #pragma unroll
        for (int q = 0; q < 4; ++q) xs[q] = xp[q];
    }
    float4 xd[5][4];
    #pragma unroll
    for (int e = 0; e < 5; ++e) {
        const float4* xp = (const float4*)(X + ((size_t)b*NPTS + dd[e])*NFEAT);
        #pragma unroll
        for (int q = 0; q < 4; ++q) xd[e][q] = xp[q];
    }
    float acc[5] = {0.f,0.f,0.f,0.f,0.f};
    for (int jj = 0; jj < 32; ++jj) {       // j = quarter*32 + jj (same order)
        const float* wr = &w1t[(jj*4 + quarter)*36];
        float4 ws0 = ((const float4*)wr)[0];
        float4 ws1 = ((const float4*)wr)[1];
        float4 ws2 = ((const float4*)wr)[2];
        float4 ws3 = ((const float4*)wr)[3];
        float4 u0  = ((const float4*)(wr+16))[0];
        float4 u1  = ((const float4*)(wr+16))[1];
        float4 u2  = ((const float4*)(wr+16))[2];
        float4 u3  = ((const float4*)(wr+16))[3];
        float w32 = wr[32];
        float b1j = wr[33];
        float w2j = wr[34];
        float sh = b1j
            + xs[0].x*ws0.x + xs[0].y*ws0.y + xs[0].z*ws0.z + xs[0].w*ws0.w
            + xs[1].x*ws1.x + xs[1].y*ws1.y + xs[1].z*ws1.z + xs[1].w*ws1.w
            + xs[2].x*ws2.x + xs[2].y*ws2.y + xs[2].z*ws2.z + xs[2].w*ws2.w
            + xs[3].x*ws3.x + xs[3].y*ws3.y + xs[3].z*ws3.z + xs[3].w*ws3.w;
        #pragma unroll
        for (int e = 0; e < 5; ++e) {
            float h = sh
                + xd[e][0].x*u0.x + xd[e][0].y*u0.y + xd[e][0].z*u0.z + xd[e][0].w*u0.w
                + xd[e][1].x*u1.x + xd[e][1].y*u1.y + xd[e][1].z*u1.z + xd[e][1].w*u1.w
                + xd[e][2].x*u2.x + xd[e][2].y*u2.y + xd[e][2].z*u2.z + xd[e][2].w*u2.w
                + xd[e][3].x*u3.x + xd[e][3].y*u3.y + xd[e][3].z*u3.z + xd[e][3].w*u3.w;
            h += vv[e]*w32;
            h = (h > 0.f) ? h : expm1f(h);
            acc[e] += h * w2j;
        }
    }
    // pairwise reduce across the 4 quarters: ((q0+q1)+(q2+q3))
    #pragma unroll
    for (int e = 0; e < 5; ++e) {
        acc[e] += __shfl_xor(acc[e], 1, 64);
        acc[e] += __shfl_xor(acc[e], 2, 64);
    }
    if (quarter != 0) return;
    float b2v = b2[0];
    #pragma unroll
    for (int e = 0; e < 5; ++e) {
        out[base + e] = 1.f/(1.f + expf(-(acc[e] + b2v)));
    }
}

extern "C" void kernel_launch(void* const* d_in, const int* in_sizes, int n_in,
                              void* d_out, int out_size, void* d_ws, size_t ws_size,
                              hipStream_t stream) {
    const float* X   = (const float*)d_in[0];
    const float* We1 = (const float*)d_in[1];
    const float* be1 = (const float*)d_in[2];
    const float* We2 = (const float*)d_in[3];
    const float* be2 = (const float*)d_in[4];
    const float* Wd1 = (const float*)d_in[5];
    const float* bd1 = (const float*)d_in[6];
    const float* Wd2 = (const float*)d_in[7];
    const float* bd2 = (const float*)d_in[8];
    const float* R   = (const float*)d_in[9];
    float* out = (float*)d_out;

    // workspace layout (~54 MB, unchanged footprint):
    // P[row][256] = [Hs|D] occupies exactly the old slab.
    u16* Pw         = (u16*)d_ws;                          // 80000*256 u16
    int*   binIdx   = (int*)(Pw + (size_t)TOTPTS*256);     // 80000
    int*   sortedIdx= binIdx + TOTPTS;                     // 80000
    int*   hist     = sortedIdx + TOTPTS;                  // 160
    float* pV       = (float*)(hist + NBATCH*NBINS);       // 160*4*512*5
    int*   pP       = (int*)(pV + (size_t)NGRP*4*PROWS*5); // 160*4*512*5

    k_enc  <<<TOTPTS/32, 256, 0, stream>>>(X, We1, be1, We2, be2, Pw, hist);
    k_bins <<<TOTPTS*4/256, 256, 0, stream>>>(Pw, R, binIdx, hist);
    k_sort <<<NBATCH*NBINS, 256, 0, stream>>>(binIdx, hist, sortedIdx);
    k_gram <<<NGRP*16, 256, 0, stream>>>(Pw, sortedIdx, pV, pP);
    k_edge <<<(NGRP*BINSZ*4+255)/256, 256, 0, stream>>>(X, Wd1, bd1, Wd2, bd2,
                                                        pV, pP, sortedIdx, out);
}

// Round 13
// 378.211 us; speedup vs baseline: 1.3318x; 1.0751x over previous
//
#include <hip/hip_runtime.h>
#include <cmath>

#define NPTS 10000
#define NBATCH 8
#define NFEAT 16
#define DDIM 128
#define NBINS 20
#define BINSZ 500
#define KSEL 5
#define EDGES_PER_BATCH (NPTS*KSEL)        // 50000
#define EDGE_TOT (NBATCH*EDGES_PER_BATCH)  // 400000
#define TOTPTS (NBATCH*NPTS)               // 80000
#define NGRP (NBATCH*NBINS)                // 160
#define PROWS 512                          // padded rows per (grp,ch) partial slab

typedef _Float16 f16x8 __attribute__((ext_vector_type(8)));
typedef float f32x4 __attribute__((ext_vector_type(4)));
typedef unsigned short u16;
typedef unsigned int u32;

// fp32 -> (Hs, D): Hs = 64*fp16(x), D = fp16((x - fp16(x)) * 64).
// Products then need no runtime scaling:
//   Hs*D = h*l, D*Hs = l*h, Hs*Hs = 4096*h*h ;  S = acc * 2^-12.
static __device__ __forceinline__ void split_f16(float v, u16& hu, u16& du) {
    _Float16 h = (_Float16)v;
    float hf = (float)h;
    if (fabsf(v) < 6.103515625e-05f) { h = (_Float16)0.0f; hf = 0.0f; }
    _Float16 Hs = h * (_Float16)64.0f;              // exact (exponent shift)
    _Float16 D  = (_Float16)((v - hf) * 64.0f);
    hu = __builtin_bit_cast(u16, Hs);
    du = __builtin_bit_cast(u16, D);
}

static __device__ __forceinline__ float f16bits(u16 u) {
    return (float)__builtin_bit_cast(_Float16, u);
}

// enc = ELU(X@W1+b1)@W2+b2, stored as P[row][256] = [Hs(128) | D(128)] f16.
// Block 0 also zeroes the bin histogram (k_bins runs after k_enc completes).
// NOTE: k_enc's expm1f is KEPT (not fast-math'd) — enc feeds bin-argmax and
// gram top-5 selection; a 1e-7 perturbation there risks index tie-flips.
// NOTE (r10/r11): fusing the bins projection here regressed 2.3-2.6x (40-48
// VGPR allocator budget -> spill or load-ILP starvation). Split wins.
__global__ __launch_bounds__(256) void k_enc(const float* __restrict__ X,
        const float* __restrict__ W1, const float* __restrict__ b1,
        const float* __restrict__ W2, const float* __restrict__ b2,
        u16* __restrict__ P, int* __restrict__ hist) {
    __shared__ float hT[128*36];
    const int tid = threadIdx.x;
    const int P0 = blockIdx.x * 32;
    if (blockIdx.x == 0 && tid < NBATCH*NBINS) hist[tid] = 0;
    #pragma unroll
    for (int i = 0; i < 16; ++i) {
        int idx = i*256 + tid;
        int p = idx >> 7;
        int j = idx & 127;
        const float* xr = X + (size_t)(P0 + p)*NFEAT;
        float h = b1[j];
        #pragma unroll
        for (int f = 0; f < 16; ++f) h += xr[f] * W1[f*128 + j];
        h = (h > 0.f) ? h : expm1f(h);
        hT[j*36 + p] = h;
    }
    __syncthreads();
    const int jt = tid & 31, pt = tid >> 5;
    const int j0 = jt*4, p0 = pt*4;
    float acc[4][4];
    #pragma unroll
    for (int ep = 0; ep < 4; ++ep)
        #pragma unroll
        for (int ej = 0; ej < 4; ++ej) acc[ep][ej] = b2[j0+ej];
    for (int k = 0; k < 128; ++k) {
        float4 hv = *(const float4*)&hT[k*36 + p0];
        float4 wv = *(const float4*)&W2[k*128 + j0];
        float hvv[4] = {hv.x,hv.y,hv.z,hv.w};
        float wvv[4] = {wv.x,wv.y,wv.z,wv.w};
        #pragma unroll
        for (int ep = 0; ep < 4; ++ep)
            #pragma unroll
            for (int ej = 0; ej < 4; ++ej) acc[ep][ej] += hvv[ep]*wvv[ej];
    }
    #pragma unroll
    for (int ep = 0; ep < 4; ++ep) {
        u16 hs[4], ds[4];
        #pragma unroll
        for (int ej = 0; ej < 4; ++ej) split_f16(acc[ep][ej], hs[ej], ds[ej]);
        size_t ro = (size_t)(P0+p0+ep)*256 + j0;
        uint2 hv2, dv2;
        hv2.x = (u32)hs[0] | ((u32)hs[1]<<16); hv2.y = (u32)hs[2] | ((u32)hs[3]<<16);
        dv2.x = (u32)ds[0] | ((u32)ds[1]<<16); dv2.y = (u32)ds[2] | ((u32)ds[3]<<16);
        *(uint2*)&P[ro]       = hv2;
        *(uint2*)&P[ro + 128] = dv2;
    }
}

// mul = enc @ R[:, :10]; bin = argmax([mul, -mul]) first-max-wins; histogram.
// Uses x' = Hs + D = 64*x — argmax invariant to the positive scale.
// 4 threads/point; Rl rows interleaved (d&31)*4+(d>>5) — conflict-free.
__global__ __launch_bounds__(256) void k_bins(const u16* __restrict__ P,
        const float* __restrict__ R,
        int* __restrict__ binIdx, int* __restrict__ hist) {
    __shared__ float Rl[1280];
    const int tid = threadIdx.x;
    for (int idx = tid; idx < 1280; idx += 256) {
        int d = idx / 10, i = idx - d*10;
        int row = (d & 31)*4 + (d >> 5);
        Rl[row*10 + i] = R[d*100 + i];
    }
    __syncthreads();
    const int gp4 = blockIdx.x*256 + tid;    // grid sized exactly: TOTPTS*4
    const int point = gp4 >> 2, seg = gp4 & 3;
    float acc[10];
    #pragma unroll
    for (int i = 0; i < 10; ++i) acc[i] = 0.f;
    const uint4* hr = (const uint4*)(P + (size_t)point*256 + seg*32);
    const uint4* lr = (const uint4*)(P + (size_t)point*256 + 128 + seg*32);
    #pragma unroll
    for (int c = 0; c < 4; ++c) {
        uint4 hv = hr[c], lv = lr[c];
        float x[8];
        x[0] = f16bits((u16)(hv.x & 0xffff)) + f16bits((u16)(lv.x & 0xffff));
        x[1] = f16bits((u16)(hv.x >> 16))    + f16bits((u16)(lv.x >> 16));
        x[2] = f16bits((u16)(hv.y & 0xffff)) + f16bits((u16)(lv.y & 0xffff));
        x[3] = f16bits((u16)(hv.y >> 16))    + f16bits((u16)(lv.y >> 16));
        x[4] = f16bits((u16)(hv.z & 0xffff)) + f16bits((u16)(lv.z & 0xffff));
        x[5] = f16bits((u16)(hv.z >> 16))    + f16bits((u16)(lv.z >> 16));
        x[6] = f16bits((u16)(hv.w & 0xffff)) + f16bits((u16)(lv.w & 0xffff));
        x[7] = f16bits((u16)(hv.w >> 16))    + f16bits((u16)(lv.w >> 16));
        #pragma unroll
        for (int e = 0; e < 8; ++e) {
            const float* rr = &Rl[((c*8 + e)*4 + seg)*10];
            #pragma unroll
            for (int i = 0; i < 10; ++i) acc[i] += x[e]*rr[i];
        }
    }
    // combine the 4 seg-partials (lanes 4k..4k+3)
    #pragma unroll
    for (int i = 0; i < 10; ++i) {
        acc[i] += __shfl_xor(acc[i], 1, 64);
        acc[i] += __shfl_xor(acc[i], 2, 64);
    }
    if (seg != 0) return;
    float best = acc[0]; int bi = 0;
    #pragma unroll
    for (int i = 1; i < 10; ++i) if (acc[i] > best) { best = acc[i]; bi = i; }
    #pragma unroll
    for (int i = 0; i < 10; ++i) { float v = -acc[i]; if (v > best) { best = v; bi = 10+i; } }
    binIdx[point] = bi;
    atomicAdd(&hist[(point/NPTS)*NBINS + bi], 1);
}

// stable counting-sort scatter: one block per (batch,bin)
__global__ __launch_bounds__(256) void k_sort(const int* __restrict__ binIdx,
        const int* __restrict__ hist, int* __restrict__ sortedIdx) {
    const int b = blockIdx.x / NBINS;
    const int bin = blockIdx.x % NBINS;
    const int tid = threadIdx.x;
    __shared__ int wtot[4];
    int off = 0;
    for (int k = 0; k < bin; ++k) off += hist[b*NBINS + k];
    const int* bptr = binIdx + b*NPTS;
    int* sptr = sortedIdx + b*NPTS;
    const int lane = tid & 63, wid = tid >> 6;
    for (int c = 0; c < 40; ++c) {
        int i = c*256 + tid;
        bool pred = (i < NPTS) && (bptr[i] == bin);
        unsigned long long mask = __ballot(pred);
        int rank = __popcll(mask & ((1ULL << lane) - 1ULL));
        if (lane == 0) wtot[wid] = __popcll(mask);
        __syncthreads();
        int prefix = 0;
        #pragma unroll
        for (int w = 0; w < 4; ++w) prefix += (w < wid) ? wtot[w] : 0;
        int total = wtot[0]+wtot[1]+wtot[2]+wtot[3];
        if (pred) sptr[off + prefix + rank] = i;
        off += total;
        __syncthreads();
    }
}

// insert (v,p) into sorted-desc 5-list, strict > (candidates arrive ascending p)
#define INS_STRICT(VV,PP,v,p) do { \
  if ((v) > VV[4]) { \
    if ((v) > VV[3]) { VV[4]=VV[3]; PP[4]=PP[3]; \
      if ((v) > VV[2]) { VV[3]=VV[2]; PP[3]=PP[2]; \
        if ((v) > VV[1]) { VV[2]=VV[1]; PP[2]=PP[1]; \
          if ((v) > VV[0]) { VV[1]=VV[0]; PP[1]=PP[0]; VV[0]=(v); PP[0]=(p); } \
          else { VV[1]=(v); PP[1]=(p); } } \
        else { VV[2]=(v); PP[2]=(p); } } \
      else { VV[3]=(v); PP[3]=(p); } } \
    else { VV[4]=(v); PP[4]=(p); } } } while(0)

// tie-aware better-than: (v desc, p asc) — exact lax.top_k semantics
#define BT(va,pa,vb,pb) (((va) > (vb)) || (((va) == (vb)) && ((pa) < (pb))))
#define INS_TIE(VV,PP,v,p) do { \
  if (BT(v,p,VV[4],PP[4])) { \
    if (BT(v,p,VV[3],PP[3])) { VV[4]=VV[3]; PP[4]=PP[3]; \
      if (BT(v,p,VV[2],PP[2])) { VV[3]=VV[2]; PP[3]=PP[2]; \
        if (BT(v,p,VV[1],PP[1])) { VV[2]=VV[1]; PP[2]=PP[1]; \
          if (BT(v,p,VV[0],PP[0])) { VV[1]=VV[0]; PP[1]=PP[0]; VV[0]=(v); PP[0]=(p); } \
          else { VV[1]=(v); PP[1]=(p); } } \
        else { VV[2]=(v); PP[2]=(p); } } \
      else { VV[3]=(v); PP[3]=(p); } } \
    else { VV[4]=(v); PP[4]=(p); } } } while(0)

// Gram via f16 MFMA with pre-scaled split operands (zero runtime scaling):
//   acc = Hs_a·D_b + D_a·Hs_b + Hs_a·Hs_b ;  S = acc·2^-12
// r5-verified structure (94 µs): T[64][132] 2-pass epilogue, LDS 35840,
// launch_bounds(256,4). r6: (256,6) spills acc (750MB scratch). r7: 32-row
// 4-pass epilogue serializes (157µs). r8: A-prefetch neutral — kept.
__global__ __launch_bounds__(256, 4) void k_gram(const u16* __restrict__ P,
        const int* __restrict__ sortedIdx, float* __restrict__ pV, int* __restrict__ pP) {
    __shared__ int gIdx[512];
    __shared__ __align__(16) union ShU {
        struct { u16 H[128][40]; u16 L[128][40]; } bs;   // 20480 B
        float T[64][132];                                // 33792 B
    } sh;
    const int tid = threadIdx.x;
    const int unit = blockIdx.x / 160;      // rowTile*4 + ch
    const int grp  = blockIdx.x - unit*160;
    const int rowTile = unit >> 2, ch = unit & 3;
    const int b = grp / NBINS, g = grp - b*NBINS;
    for (int i = tid; i < 512; i += 256) gIdx[i] = sortedIdx[b*NPTS + g*500 + min(i, 499)];
    __syncthreads();

    const int w    = tid >> 6;              // wave 0..3: rows w*32..w*32+31
    const int lane = tid & 63;
    const int l15  = lane & 15, l4 = lane >> 4;
    const int rowBase = rowTile * 128;

    const size_t ebase = (size_t)b * NPTS * 256;   // halfwords
    const u16* PB = P + ebase;
    const u16* pA0 = PB + (size_t)gIdx[rowBase + w*32 +      l15]*256 + l4*8;
    const u16* pA1 = PB + (size_t)gIdx[rowBase + w*32 + 16 + l15]*256 + l4*8;

    // stager role: thread t copies the 64B ks-chunk of col (t>>1), part (t&1)
    const int scol = tid >> 1, spart = tid & 1;
    const u16* pS = PB + (size_t)gIdx[ch*128 + scol]*256 + spart*128;
    u16* dS = spart ? &sh.bs.L[scol][0] : &sh.bs.H[scol][0];

    f32x4 acc[2][8];
    const f32x4 z4 = {0.f, 0.f, 0.f, 0.f};
    #pragma unroll
    for (int rf = 0; rf < 2; ++rf)
        #pragma unroll
        for (int cf = 0; cf < 8; ++cf) acc[rf][cf] = z4;

    // prologue: stage B regs for ks=0 and A fragments for ks=0
    uint4 s0, s1, s2, s3;
    { const uint4* s = (const uint4*)pS; s0 = s[0]; s1 = s[1]; s2 = s[2]; s3 = s[3]; }
    f16x8 aH0 = *(const f16x8*)(pA0 + 0);
    f16x8 aD0 = *(const f16x8*)(pA0 + 128);
    f16x8 aH1 = *(const f16x8*)(pA1 + 0);
    f16x8 aD1 = *(const f16x8*)(pA1 + 128);

    #pragma unroll
    for (int ks = 0; ks < 4; ++ks) {
        __syncthreads();                    // prior k-step's LDS reads done
        {   // write staged B regs (data already in flight / in regs)
            uint4* d = (uint4*)dS;
            d[0] = s0; d[1] = s1; d[2] = s2; d[3] = s3;
        }
        if (ks < 3) {                       // prefetch next B chunk under MFMA
            const uint4* s = (const uint4*)(pS + (ks+1)*32);
            s0 = s[0]; s1 = s[1]; s2 = s[2]; s3 = s[3];
        }
        __syncthreads();                    // staged data visible
        #pragma unroll
        for (int cf = 0; cf < 8; ++cf) {
            const int col = cf*16 + l15;
            const f16x8 bH = *(const f16x8*)&sh.bs.H[col][l4*8];
            const f16x8 bD = *(const f16x8*)&sh.bs.L[col][l4*8];
            acc[0][cf] = __builtin_amdgcn_mfma_f32_16x16x32_f16(aH0, bD, acc[0][cf], 0, 0, 0);
            acc[1][cf] = __builtin_amdgcn_mfma_f32_16x16x32_f16(aH1, bD, acc[1][cf], 0, 0, 0);
            acc[0][cf] = __builtin_amdgcn_mfma_f32_16x16x32_f16(aD0, bH, acc[0][cf], 0, 0, 0);
            acc[1][cf] = __builtin_amdgcn_mfma_f32_16x16x32_f16(aD1, bH, acc[1][cf], 0, 0, 0);
            acc[0][cf] = __builtin_amdgcn_mfma_f32_16x16x32_f16(aH0, bH, acc[0][cf], 0, 0, 0);
            acc[1][cf] = __builtin_amdgcn_mfma_f32_16x16x32_f16(aH1, bH, acc[1][cf], 0, 0, 0);
        }
        if (ks < 3) {                       // prefetch A for ks+1
            const int oH = (ks+1)*32;
            const int oD = 128 + (ks+1)*32;
            aH0 = *(const f16x8*)(pA0 + oH);
            aD0 = *(const f16x8*)(pA0 + oD);
            aH1 = *(const f16x8*)(pA1 + oH);
            aD1 = *(const f16x8*)(pA1 + oD);
        }
    }
    __syncthreads();                        // k-loop LDS reads done; reuse as T

    // ---- epilogue: per rf-half, LDS transpose then 4-thread/row top-5 ----
    const float sc = 2.44140625e-4f;        // 2^-12, applied to survivors only
    const int rT = tid >> 2;                // 0..63: T-row this thread reduces
    const int q  = tid & 3;                 // chunk interleave c4 = 4t+q
    const bool chk = (ch == 3);             // chunks >= 29 invalid when ch==3
    #pragma unroll
    for (int rf = 0; rf < 2; ++rf) {
        #pragma unroll
        for (int cf = 0; cf < 8; ++cf) {
            const int col = cf*16 + l15;
            const int r0  = w*16 + l4*4;
            #pragma unroll
            for (int j = 0; j < 4; ++j) sh.T[r0+j][col] = acc[rf][cf][j];
        }
        __syncthreads();
        float lv[5]; int lp[5];
        #pragma unroll
        for (int p5 = 0; p5 < 5; ++p5) { lv[p5] = -3.4e38f; lp[p5] = 0x7fffffff; }
        const float* Tr = &sh.T[rT][0];
        #pragma unroll
        for (int t = 0; t < 8; ++t) {
            const int c4 = t*4 + q;         // ascending cpos per thread
            if (!chk || c4 < 29) {          // 116 valid cols = chunks 0..28
                float4 v4 = *(const float4*)&Tr[c4*4];
                float vv4[4] = {v4.x, v4.y, v4.z, v4.w};
                #pragma unroll
                for (int e = 0; e < 4; ++e)
                    INS_STRICT(lv, lp, vv4[e], ch*128 + c4*4 + e);
            }
        }
        #pragma unroll
        for (int m = 1; m < 4; m <<= 1) {
            float qv[5]; int qp[5];
            #pragma unroll
            for (int p5 = 0; p5 < 5; ++p5) {
                qv[p5] = __shfl_xor(lv[p5], m, 64);
                qp[p5] = __shfl_xor(lp[p5], m, 64);
            }
            #pragma unroll
            for (int p5 = 0; p5 < 5; ++p5) INS_TIE(lv, lp, qv[p5], qp[p5]);
        }
        if (q == 0) {
            const int rpos = rowBase + (rT>>4)*32 + rf*16 + (rT&15);
            if (rpos < 500) {
                const int pbase = ((grp*4 + ch)*PROWS + rpos)*5;
                #pragma unroll
                for (int p5 = 0; p5 < 5; ++p5) { pV[pbase+p5] = lv[p5]*sc; pP[pbase+p5] = lp[p5]; }
            }
        }
        __syncthreads();
    }
}

// fused merge + edge MLP, 4 threads per src point.
// w1t rows interleaved r=(j&31)*4+(j>>5) — quarters read adjacent rows
// (disjoint bank-quads, conflict-free). b1/W2 folded into row slots 33/34.
// v13: transcendentals -> hw-fast __expf. All three sites are POST-selection
// (edge values only; src/dst index outputs computed before and independently)
// so no tie-flip risk. expm1f(h) -> __expf(h)-1 (~1e-7 abs dev, inside tol);
// ~160 libm expm1 calls/thread (~15-30 VALU each) become ~2 instr each.
__global__ __launch_bounds__(256) void k_edge(const float* __restrict__ X,
        const float* __restrict__ W1, const float* __restrict__ b1,
        const float* __restrict__ W2, const float* __restrict__ b2,
        const float* __restrict__ pV, const int* __restrict__ pP,
        const int* __restrict__ sortedIdx, float* __restrict__ out) {
    __shared__ float w1t[128*36];
    const int tid = threadIdx.x;
    for (int idx = tid; idx < 33*128; idx += 256) {
        int f = idx >> 7, j = idx & 127;
        w1t[((j & 31)*4 + (j >> 5))*36 + f] = W1[idx];
    }
    if (tid < 128) {
        int r = ((tid & 31)*4 + (tid >> 5))*36;
        w1t[r + 33] = b1[tid];
        w1t[r + 34] = W2[tid];
    }
    __syncthreads();
    int rid4 = blockIdx.x*256 + tid;
    if (rid4 >= NGRP*BINSZ*4) return;
    const int rid = rid4 >> 2, quarter = rid4 & 3;
    const int grp = rid / BINSZ;
    const int rowLocal = rid - grp*BINSZ;
    const int b = grp / NBINS, g = grp - b*NBINS;
    // ---- merge 4 ch-partials (duplicated across the 4 quarters; deterministic) ----
    float lv[5]; int lp[5];
    {
        int pbase = (grp*4*PROWS + rowLocal)*5;
        #pragma unroll
        for (int j = 0; j < 5; ++j) { lv[j] = pV[pbase+j]; lp[j] = pP[pbase+j]; }
    }
    #pragma unroll
    for (int chh = 1; chh < 4; ++chh) {
        int pbase = ((grp*4 + chh)*PROWS + rowLocal)*5;
        #pragma unroll
        for (int j = 0; j < 5; ++j) {
            float v = pV[pbase+j]; int p = pP[pbase+j];
            INS_TIE(lv, lp, v, p);
        }
    }
    const int* sIdx = sortedIdx + b*NPTS + g*BINSZ;
    const int src = sIdx[rowLocal];
    int dd[5]; float vv[5];
    #pragma unroll
    for (int j = 0; j < 5; ++j) {
        dd[j] = sIdx[lp[j]];
        vv[j] = 1.f/(1.f + __expf(-lv[j]));
    }
    #define CSWAP(i,j) { if (dd[i] > dd[j]) { int td=dd[i];dd[i]=dd[j];dd[j]=td; \
                         float tf=vv[i];vv[i]=vv[j];vv[j]=tf; } }
    CSWAP(0,1) CSWAP(3,4) CSWAP(2,4) CSWAP(2,3) CSWAP(1,4)
    CSWAP(0,3) CSWAP(0,2) CSWAP(1,3) CSWAP(1,2)
    #undef CSWAP
    const int base = b*EDGES_PER_BATCH + src*5;
    if (quarter == 0) {
        #pragma unroll
        for (int e = 0; e < 5; ++e) {
            out[EDGE_TOT   + base + e] = (float)src;
            out[2*EDGE_TOT + base + e] = (float)dd[e];
        }
    }
    // ---- edge MLP over j-range [quarter*32, quarter*32+32) ----
    float4 xs[4];
    {
        const float4* xp = (const float4*)(X + ((size_t)b*NPTS + src)*NFEAT);
        #pragma unroll
        for (int q = 0; q < 4; ++q) xs[q] = xp[q];
    }
    float4 xd[5][4];
    #pragma unroll
    for (int e = 0; e < 5; ++e) {
        const float4* xp = (const float4*)(X + ((size_t)b*NPTS + dd[e])*NFEAT);
        #pragma unroll
        for (int q = 0; q < 4; ++q) xd[e][q] = xp[q];
    }
    float acc[5] = {0.f,0.f,0.f,0.f,0.f};
    for (int jj = 0; jj < 32; ++jj) {       // j = quarter*32 + jj (same order)
        const float* wr = &w1t[(jj*4 + quarter)*36];
        float4 ws0 = ((const float4*)wr)[0];
        float4 ws1 = ((const float4*)wr)[1];
        float4 ws2 = ((const float4*)wr)[2];
        float4 ws3 = ((const float4*)wr)[3];
        float4 u0  = ((const float4*)(wr+16))[0];
        float4 u1  = ((const float4*)(wr+16))[1];
        float4 u2  = ((const float4*)(wr+16))[2];
        float4 u3  = ((const float4*)(wr+16))[3];
        float w32 = wr[32];
        float b1j = wr[33];
        float w2j = wr[34];
        float sh = b1j
            + xs[0].x*ws0.x + xs[0].y*ws0.y + xs[0].z*ws0.z + xs[0].w*ws0.w
            + xs[1].x*ws1.x + xs[1].y*ws1.y + xs[1].z*ws1.z + xs[1].w*ws1.w
            + xs[2].x*ws2.x + xs[2].y*ws2.y + xs[2].z*ws2.z + xs[2].w*ws2.w
            + xs[3].x*ws3.x + xs[3].y*ws3.y + xs[3].z*ws3.z + xs[3].w*ws3.w;
        #pragma unroll
        for (int e = 0; e < 5; ++e) {
            float h = sh
                + xd[e][0].x*u0.x + xd[e][0].y*u0.y + xd[e][0].z*u0.z + xd[e][0].w*u0.w
                + xd[e][1].x*u1.x + xd[e][1].y*u1.y + xd[e][1].z*u1.z + xd[e][1].w*u1.w
                + xd[e][2].x*u2.x + xd[e][2].y*u2.y + xd[e][2].z*u2.z + xd[e][2].w*u2.w
                + xd[e][3].x*u3.x + xd[e][3].y*u3.y + xd[e][3].z*u3.z + xd[e][3].w*u3.w;
            h += vv[e]*w32;
            h = (h > 0.f) ? h : (__expf(h) - 1.0f);
            acc[e] += h * w2j;
        }
    }
    // pairwise reduce across the 4 quarters: ((q0+q1)+(q2+q3))
    #pragma unroll
    for (int e = 0; e < 5; ++e) {
        acc[e] += __shfl_xor(acc[e], 1, 64);
        acc[e] += __shfl_xor(acc[e], 2, 64);
    }
    if (quarter != 0) return;
    float b2v = b2[0];
    #pragma unroll
    for (int e = 0; e < 5; ++e) {
        out[base + e] = 1.f/(1.f + __expf(-(acc[e] + b2v)));
    }
}

extern "C" void kernel_launch(void* const* d_in, const int* in_sizes, int n_in,
                              void* d_out, int out_size, void* d_ws, size_t ws_size,
                              hipStream_t stream) {
    const float* X   = (const float*)d_in[0];
    const float* We1 = (const float*)d_in[1];
    const float* be1 = (const float*)d_in[2];
    const float* We2 = (const float*)d_in[3];
    const float* be2 = (const float*)d_in[4];
    const float* Wd1 = (const float*)d_in[5];
    const float* bd1 = (const float*)d_in[6];
    const float* Wd2 = (const float*)d_in[7];
    const float* bd2 = (const float*)d_in[8];
    const float* R   = (const float*)d_in[9];
    float* out = (float*)d_out;

    // workspace layout (~54 MB, unchanged footprint):
    // P[row][256] = [Hs|D] occupies exactly the old slab.
    u16* Pw         = (u16*)d_ws;                          // 80000*256 u16
    int*   binIdx   = (int*)(Pw + (size_t)TOTPTS*256);     // 80000
    int*   sortedIdx= binIdx + TOTPTS;                     // 80000
    int*   hist     = sortedIdx + TOTPTS;                  // 160
    float* pV       = (float*)(hist + NBATCH*NBINS);       // 160*4*512*5
    int*   pP       = (int*)(pV + (size_t)NGRP*4*PROWS*5); // 160*4*512*5

    k_enc  <<<TOTPTS/32, 256, 0, stream>>>(X, We1, be1, We2, be2, Pw, hist);
    k_bins <<<TOTPTS*4/256, 256, 0, stream>>>(Pw, R, binIdx, hist);
    k_sort <<<NBATCH*NBINS, 256, 0, stream>>>(binIdx, hist, sortedIdx);
    k_gram <<<NGRP*16, 256, 0, stream>>>(Pw, sortedIdx, pV, pP);
    k_edge <<<(NGRP*BINSZ*4+255)/256, 256, 0, stream>>>(X, Wd1, bd1, Wd2, bd2,
                                                        pV, pP, sortedIdx, out);
}